// Round 5
// baseline (670.824 us; speedup 1.0000x reference)
//
#include <hip/hip_runtime.h>
#include <hip/hip_bf16.h>
#include <math.h>

typedef __bf16 bf16;
typedef __bf16 bf16x4 __attribute__((ext_vector_type(4)));
typedef __bf16 bf16x8 __attribute__((ext_vector_type(8)));
typedef float floatx4 __attribute__((ext_vector_type(4)));

#define BB 2
#define LL 1024
#define DD 768
#define DI 1536
#define MROWS 2048   // B*L
#define NXP 80       // dt_rank + 2*d_state
#define DTRANK 48
#define DTPAD 64     // dt K padded to 64
#define DSTATE 16
#define NC 16        // scan chunks
#define CLEN 64      // scan chunk length (NC*CLEN == LL)
#define KSPLIT 16    // x_proj split-K factor (K-seg = 96)
#define OPKS 4       // out_proj split-K factor (K-seg = 384)
#define LOG2E 1.4426950408889634f
#define TROW 132     // floats per sdpT/sbcT row (128 data + 4 pad)
#define SYROW 68     // floats per syT row

// async global->LDS, 16 B per lane; lds dest must be wave-uniform base (+lane*16)
__device__ __forceinline__ void ld16(void* lds, const void* g) {
    __builtin_amdgcn_global_load_lds(
        (const __attribute__((address_space(1))) void*)g,
        (__attribute__((address_space(3))) void*)lds, 16, 0, 0);
}

// drain this wave's outstanding async global_load_lds before signalling barrier.
__device__ __forceinline__ void wait_vm0() {
    asm volatile("s_waitcnt vmcnt(0)" ::: "memory");
}

// DPP row-reduce over 16 lanes (one DPP row): lane 0 of each row gets the sum.
__device__ __forceinline__ float row16_sum(float x) {
    float t;
    t = __int_as_float(__builtin_amdgcn_update_dpp(0, __float_as_int(x), 0x111, 0xF, 0xF, true)); x += t;
    t = __int_as_float(__builtin_amdgcn_update_dpp(0, __float_as_int(x), 0x112, 0xF, 0xF, true)); x += t;
    t = __int_as_float(__builtin_amdgcn_update_dpp(0, __float_as_int(x), 0x114, 0xF, 0xF, true)); x += t;
    t = __int_as_float(__builtin_amdgcn_update_dpp(0, __float_as_int(x), 0x118, 0xF, 0xF, true)); x += t;
    return x;
}

// raw v_exp_f32 (no ocml denormal fixup; exp2(x<-126) flushes to 0 which is fine here)
__device__ __forceinline__ float exp2_raw(float x) {
#if __has_builtin(__builtin_amdgcn_exp2f)
    return __builtin_amdgcn_exp2f(x);
#else
    float r; asm("v_exp_f32 %0, %1" : "=v"(r) : "v"(x)); return r;
#endif
}

// ---------------------------------------------------------------- all weight cvt in one kernel
#define N1 (4 * 3072 * 768)
#define N2 (4 * NXP * DI)
#define N3 (4 * DI * DTPAD)
#define N4 (4 * DD * DI)
__global__ __launch_bounds__(256) void cvt_all_k(const float* __restrict__ in_proj_w,
                                                 const float* __restrict__ x_proj_w,
                                                 const float* __restrict__ dt_proj_w,
                                                 const float* __restrict__ out_proj_w,
                                                 bf16* __restrict__ w_in,
                                                 bf16* __restrict__ w_xp,
                                                 bf16* __restrict__ w_dt,
                                                 bf16* __restrict__ w_out) {
    int i = blockIdx.x * 256 + threadIdx.x;
    if (i < N1) { w_in[i] = (bf16)in_proj_w[i]; return; }
    i -= N1;
    if (i < N2) { w_xp[i] = (bf16)x_proj_w[i]; return; }
    i -= N2;
    if (i < N3) {
        int row = i >> 6, c = i & 63;
        w_dt[i] = (c < DTRANK) ? (bf16)dt_proj_w[row * DTRANK + c] : (bf16)0.f;
        return;
    }
    i -= N3;
    if (i < N4) w_out[i] = (bf16)out_proj_w[i];
}

// ---------------------------------------------------------------- rmsnorm -> bf16 (layer 0 only)
__global__ __launch_bounds__(256) void rmsnorm_k(const float* __restrict__ x,
                                                 const float* __restrict__ w,
                                                 bf16* __restrict__ out) {
    int row = blockIdx.x;
    const float* xr = x + (size_t)row * DD;
    int tid = threadIdx.x;
    float v[3]; float ss = 0.f;
    for (int j = 0; j < 3; j++) { v[j] = xr[tid + j * 256]; ss += v[j] * v[j]; }
    for (int o = 1; o < 64; o <<= 1) ss += __shfl_xor(ss, o, 64);
    __shared__ float sred[4];
    if ((tid & 63) == 0) sred[tid >> 6] = ss;
    __syncthreads();
    float scale = rsqrtf((sred[0] + sred[1] + sred[2] + sred[3]) / (float)DD + 1e-6f);
    for (int j = 0; j < 3; j++) {
        int c = tid + j * 256;
        out[(size_t)row * DD + c] = (bf16)(v[j] * scale * w[c]);
    }
}

// ---------------------------------------------------------------- GEMM: C = A @ W^T
// MODE 1: store bf16 | MODE 5: split-K partials f32
template <int MODE>
__global__ __launch_bounds__(256) void gemm_bt(const bf16* __restrict__ A,
                                               const bf16* __restrict__ W,
                                               float* __restrict__ Cf,
                                               bf16* __restrict__ Cb,
                                               int M, int N, int K) {
    __shared__ bf16 As[128][32];
    __shared__ bf16 Ws[128][32];
    const int tid  = threadIdx.x;
    const int m0   = blockIdx.x * 128;
    const int n0   = blockIdx.y * 128;
    const int wave = tid >> 6;
    const int lane = tid & 63;
    const int wm   = (wave >> 1) * 64;
    const int wn   = (wave & 1) * 64;
    const int lrow = lane & 15;
    const int quad = lane >> 4;

    int kbeg = 0, kend = K;
    if constexpr (MODE == 5) {
        int kseg = K / gridDim.z;
        kbeg = blockIdx.z * kseg;
        kend = kbeg + kseg;
        Cf  += (size_t)blockIdx.z * M * N;
    }

    floatx4 acc[4][4];
    for (int mi = 0; mi < 4; mi++)
        for (int ni = 0; ni < 4; ni++) acc[mi][ni] = (floatx4){0.f, 0.f, 0.f, 0.f};

    const int r0  = tid >> 2;        // 0..63
    const int r1  = r0 + 64;         // 64..127
    const int seg = (tid & 3) * 8;   // 0,8,16,24
    char* asb0 = (char*)As + wave * 1024;
    char* asb1 = (char*)As + 4096 + wave * 1024;
    char* wsb0 = (char*)Ws + wave * 1024;
    char* wsb1 = (char*)Ws + 4096 + wave * 1024;

    for (int kb = kbeg; kb < kend; kb += 32) {
        int gk = kb + seg;
        __syncthreads();   // previous iteration's LDS reads done
        ld16(asb0, A + (size_t)(m0 + r0) * K + gk);
        ld16(asb1, A + (size_t)(m0 + r1) * K + gk);
        ld16(wsb0, W + (size_t)(n0 + r0) * K + gk);
        ld16(wsb1, W + (size_t)(n0 + r1) * K + gk);
        wait_vm0();        // this wave's async LDS fills landed
        __syncthreads();   // all waves' fills landed -> tiles ready
        bf16x8 af[4], wf[4];
        for (int mi = 0; mi < 4; mi++) af[mi] = *(const bf16x8*)&As[wm + mi * 16 + lrow][quad * 8];
        for (int ni = 0; ni < 4; ni++) wf[ni] = *(const bf16x8*)&Ws[wn + ni * 16 + lrow][quad * 8];
        for (int mi = 0; mi < 4; mi++)
            for (int ni = 0; ni < 4; ni++)
                acc[mi][ni] = __builtin_amdgcn_mfma_f32_16x16x32_bf16(af[mi], wf[ni], acc[mi][ni], 0, 0, 0);
    }
    for (int mi = 0; mi < 4; mi++) {
        int rowb = m0 + wm + mi * 16 + quad * 4;
        for (int ni = 0; ni < 4; ni++) {
            int col = n0 + wn + ni * 16 + lrow;
            for (int r = 0; r < 4; r++) {
                int row = rowb + r;
                float v = acc[mi][ni][r];
                if constexpr (MODE == 1) Cb[(size_t)row * N + col] = (bf16)v;
                else                     Cf[(size_t)row * N + col] = v;
            }
        }
    }
}

// ---------------------------------------------------------------- out_proj partials + residual + NEXT layer rmsnorm (fused)
__global__ __launch_bounds__(256) void op_reduce_norm_k(const float* __restrict__ part,
                                                        const float* __restrict__ resid,
                                                        const float* __restrict__ nw,
                                                        float* __restrict__ xout,
                                                        bf16* __restrict__ xnb) {
    int row = blockIdx.x;
    int tid = threadIdx.x;
    float v[3]; float ss = 0.f;
    for (int j = 0; j < 3; j++) {
        int c = tid + j * 256;
        size_t idx = (size_t)row * DD + c;
        float s = resid[idx];
        for (int ks = 0; ks < OPKS; ks++) s += part[(size_t)ks * MROWS * DD + idx];
        v[j] = s;
        xout[idx] = s;
        ss += s * s;
    }
    for (int o = 1; o < 64; o <<= 1) ss += __shfl_xor(ss, o, 64);
    __shared__ float sred[4];
    if ((tid & 63) == 0) sred[tid >> 6] = ss;
    __syncthreads();
    float scale = rsqrtf((sred[0] + sred[1] + sred[2] + sred[3]) / (float)DD + 1e-6f);
    for (int j = 0; j < 3; j++) {
        int c = tid + j * 256;
        xnb[(size_t)row * DD + c] = (bf16)(v[j] * scale * nw[c]);
    }
}

// ---------------------------------------------------------------- x_proj split-K GEMM
__global__ __launch_bounds__(256) void gemm_xp(const bf16* __restrict__ A,
                                               const bf16* __restrict__ W,
                                               float* __restrict__ part) {
    __shared__ bf16 As[64][40];
    __shared__ bf16 Ws[128][40];
    const int tid  = threadIdx.x;
    const int m0   = blockIdx.x * 64;
    const int ks   = blockIdx.y;
    const int k0   = ks * (DI / KSPLIT);
    const int wave = tid >> 6;
    const int lane = tid & 63;
    const int lrow = lane & 15;
    const int quad = lane >> 4;
    const int wm   = wave * 16;

    floatx4 acc[5];
    for (int ni = 0; ni < 5; ni++) acc[ni] = (floatx4){0.f, 0.f, 0.f, 0.f};

    const int ra  = tid >> 2;
    const int rw1 = ra + 64;
    const int seg = (tid & 3) * 8;

    for (int kb = 0; kb < DI / KSPLIT; kb += 32) {
        int gk = k0 + kb + seg;
        bf16x8 va = *(const bf16x8*)(A + (size_t)(m0 + ra) * DI + gk);
        bf16x8 vw0, vw1;
        if (ra < NXP) vw0 = *(const bf16x8*)(W + (size_t)ra * DI + gk);
        else          for (int j = 0; j < 8; j++) vw0[j] = (bf16)0.f;
        if (rw1 < NXP) vw1 = *(const bf16x8*)(W + (size_t)rw1 * DI + gk);
        else           for (int j = 0; j < 8; j++) vw1[j] = (bf16)0.f;
        __syncthreads();
        *(bf16x8*)&As[ra][seg]  = va;
        *(bf16x8*)&Ws[ra][seg]  = vw0;
        *(bf16x8*)&Ws[rw1][seg] = vw1;
        __syncthreads();
        bf16x8 af = *(const bf16x8*)&As[wm + lrow][quad * 8];
        for (int ni = 0; ni < 5; ni++) {
            bf16x8 wf = *(const bf16x8*)&Ws[ni * 16 + lrow][quad * 8];
            acc[ni] = __builtin_amdgcn_mfma_f32_16x16x32_bf16(af, wf, acc[ni], 0, 0, 0);
        }
    }
    float* pout = part + (size_t)ks * MROWS * NXP;
    for (int ni = 0; ni < 5; ni++) {
        int col = ni * 16 + lrow;
        for (int r = 0; r < 4; r++) {
            int row = m0 + wm + quad * 4 + r;
            pout[(size_t)row * NXP + col] = acc[ni][r];
        }
    }
}

// reduce split-K partials -> xdbl f32 + padded bf16 dt
__global__ __launch_bounds__(256) void xp_reduce_k(const float* __restrict__ part,
                                                   float* __restrict__ xdbl,
                                                   bf16* __restrict__ dtbf) {
    int idx = blockIdx.x * 256 + threadIdx.x;
    if (idx >= MROWS * NXP) return;
    float s = 0.f;
    for (int j = 0; j < KSPLIT; j++) s += part[(size_t)j * MROWS * NXP + idx];
    xdbl[idx] = s;
    int m = idx / NXP, c = idx - m * NXP;
    if (c < DTRANK)      dtbf[m * DTPAD + c] = (bf16)s;
    else if (c < DTPAD)  dtbf[m * DTPAD + c] = (bf16)0.f;
}

// ---------------------------------------------------------------- causal depthwise conv + silu + gate (4-wide, bf16 outputs)
__global__ __launch_bounds__(256) void conv_silu_k(const bf16* __restrict__ xz,
                                                   const float* __restrict__ cw,
                                                   const float* __restrict__ cb,
                                                   bf16* __restrict__ xcb,
                                                   bf16* __restrict__ gzb) {
    int t = blockIdx.x * 256 + threadIdx.x;
    if (t >= MROWS * (DI / 4)) return;
    int m = t / (DI / 4);
    int d = (t - m * (DI / 4)) * 4;
    int l = m & (LL - 1);
    float acc[4];
    floatx4 cwv[4];
    for (int q = 0; q < 4; q++) {
        acc[q] = cb[d + q];
        cwv[q] = *(const floatx4*)&cw[(d + q) * 4];
    }
    for (int k = 0; k < 4; k++) {
        int lp = l - 3 + k;
        if (lp >= 0) {
            bf16x4 v = *(const bf16x4*)&xz[(size_t)(m - 3 + k) * (2 * DI) + d];
            for (int q = 0; q < 4; q++) acc[q] += (float)v[q] * cwv[q][k];
        }
    }
    bf16x4 xo, go;
    bf16x4 z4 = *(const bf16x4*)&xz[(size_t)m * (2 * DI) + DI + d];
    for (int q = 0; q < 4; q++) {
        float s = acc[q] / (1.f + __expf(-acc[q]));
        xo[q] = (bf16)s;
        float zv = (float)z4[q];
        go[q] = (bf16)(zv / (1.f + __expf(-zv)));
    }
    *(bf16x4*)&xcb[(size_t)m * DI + d] = xo;
    *(bf16x4*)&gzb[(size_t)m * DI + d] = go;
}

// ---------------------------------------------------------------- chunk-parallel 2-phase selective scan (v5)
// R4 post-mortem: scan2 at 53% VALUBusy — per-block fixed costs (exposed stage,
// LDS round-trip for MFMA operands, repack, barriers) ~45% of block time.
// v5: (a) MFMA A/B fragments + B/C loaded straight to REGISTERS (dt/wdt/xdbl
// are L2-resident; each frag is one contiguous 16B load) — deletes Adt/Bdt/
// sbcraw from LDS and the repack pass; scan2 LDS 40K->33.5K -> 4 blocks/CU.
// (b) 2 chunks per block (grid z=NC/2): chunk c+1's reg loads + sxc/sgz DMA
// issue right after chunk c's pack barrier and land under the 64-step scan —
// second chunk's staging is fully hidden, prologue amortized; h carries in
// registers into the second chunk.
// Phase 1: chunk-local scan from h=0 -> (P, S).
__global__ __launch_bounds__(256) void scan1_k(const bf16* __restrict__ dtb,
                                               const bf16* __restrict__ wdt,
                                               const float* __restrict__ dtbias,
                                               const bf16* __restrict__ xcb,
                                               const float* __restrict__ xdbl,
                                               const float* __restrict__ A_log,
                                               float* __restrict__ Pbuf,
                                               float* __restrict__ Sbuf) {
    const int b   = blockIdx.y;
    const int d0  = blockIdx.x * 16;
    const int c0  = blockIdx.z * 2;
    const int tid = threadIdx.x;
    const int dl  = tid >> 4;
    const int n   = tid & 15;
    const int wv  = tid >> 6;
    const int lane = tid & 63;
    const int lr  = lane & 15;
    const int q   = lane >> 4;

    const float a2 = -__expf(A_log[(size_t)(d0 + dl) * DSTATE + n]) * LOG2E;
    const float bi = dtbias[d0 + lr];

    __shared__ __align__(16) bf16  sxc[CLEN][16];   // conv out (DMA)
    __shared__ __align__(16) float sdpT[16][TROW];  // [d][2i]=(dv), [2i+1]=(dv*xc)
    __shared__ __align__(16) float sbT[16][68];     // [n][i]=B

    // persistent w_dt fragments (regs, L2-resident)
    const bf16x8 wf0 = *(const bf16x8*)&wdt[(size_t)(d0 + lr) * DTPAD + q * 8];
    const bf16x8 wf1 = *(const bf16x8*)&wdt[(size_t)(d0 + lr) * DTPAD + 32 + q * 8];

    auto ldA = [&](int l0, bf16x8& a0, bf16x8& a1) {
        const bf16* r = &dtb[(size_t)(b * LL + l0 + 16 * wv + lr) * DTPAD + q * 8];
        a0 = *(const bf16x8*)r;
        a1 = *(const bf16x8*)(r + 32);
    };
    auto ldB = [&](int l0, float* Bv) {
        #pragma unroll
        for (int k2 = 0; k2 < 4; ++k2) {
            int ii = (tid + 256 * k2) >> 4;
            Bv[k2] = xdbl[(size_t)(b * LL + l0 + ii) * NXP + DTRANK + n];
        }
    };
    auto dma_x = [&](int l0) {
        if (tid < 128) {
            int r2 = tid >> 1, c2 = tid & 1;
            ld16((char*)&sxc[0][0] + (tid & ~63) * 16,
                 xcb + (size_t)(b * LL + l0 + r2) * DI + d0 + c2 * 8);
        }
    };
    auto pack = [&](bf16x8 a0, bf16x8 a1, const float* Bv) {
        floatx4 dacc = (floatx4){0.f, 0.f, 0.f, 0.f};
        dacc = __builtin_amdgcn_mfma_f32_16x16x32_bf16(a0, wf0, dacc, 0, 0, 0);
        dacc = __builtin_amdgcn_mfma_f32_16x16x32_bf16(a1, wf1, dacc, 0, 0, 0);
        float vv[4], xvv[4];
        #pragma unroll
        for (int r = 0; r < 4; ++r) {
            int l = 16 * wv + q * 4 + r;
            float v = dacc[r] + bi;
            v = (v > 20.f) ? v : log1pf(__expf(v));
            vv[r] = v; xvv[r] = (float)sxc[l][lr];
        }
        int L0 = 16 * wv + q * 4;
        *(float4*)&sdpT[lr][2 * L0] =
            make_float4(vv[0], vv[0] * xvv[0], vv[1], vv[1] * xvv[1]);
        *(float4*)&sdpT[lr][2 * L0 + 4] =
            make_float4(vv[2], vv[2] * xvv[2], vv[3], vv[3] * xvv[3]);
        #pragma unroll
        for (int k2 = 0; k2 < 4; ++k2) {
            int ii = (tid + 256 * k2) >> 4;
            sbT[n][ii] = Bv[k2];
        }
    };
    auto scanloc = [&](int c) {
        float h = 0.f, sd = 0.f;
        const float4* dpr = (const float4*)&sdpT[dl][0];
        const float4* bpr = (const float4*)&sbT[n][0];
        float4 dA[4], dB2[4], bA[2], bB2[2];
        #pragma unroll
        for (int t = 0; t < 4; ++t) dA[t] = dpr[t];
        #pragma unroll
        for (int t = 0; t < 2; ++t) bA[t] = bpr[t];
        #pragma unroll
        for (int g = 0; g < 8; ++g) {
            if (g + 1 < 8) {
                #pragma unroll
                for (int t = 0; t < 4; ++t) {
                    if ((g & 1) == 0) dB2[t] = dpr[(g + 1) * 4 + t];
                    else              dA[t]  = dpr[(g + 1) * 4 + t];
                }
                #pragma unroll
                for (int t = 0; t < 2; ++t) {
                    if ((g & 1) == 0) bB2[t] = bpr[(g + 1) * 2 + t];
                    else              bA[t]  = bpr[(g + 1) * 2 + t];
                }
            }
            #pragma unroll
            for (int i = 0; i < 8; ++i) {
                float4 v = ((g & 1) == 0) ? dA[i >> 1] : dB2[i >> 1];
                float4 w = ((g & 1) == 0) ? bA[i >> 2] : bB2[i >> 2];
                float dvx = (i & 1) ? v.z : v.x;
                float dpy = (i & 1) ? v.w : v.y;
                float bx  = ((i & 3) == 0) ? w.x : ((i & 3) == 1) ? w.y
                          : ((i & 3) == 2) ? w.z : w.w;
                float e = exp2_raw(dvx * a2);
                h = __builtin_fmaf(e, h, dpy * bx);
                sd += dvx;
            }
        }
        size_t o = (((size_t)c * BB + b) * DI + (d0 + dl)) * DSTATE + n;
        Pbuf[o] = exp2_raw(a2 * sd);
        Sbuf[o] = h;
    };

    const int l0 = c0 * CLEN;
    bf16x8 a0, a1, a0n, a1n;
    float Bv[4], Bvn[4];

    ldA(l0, a0, a1);
    ldB(l0, Bv);
    dma_x(l0);
    wait_vm0();
    __syncthreads();

    pack(a0, a1, Bv);
    __syncthreads();
    ldA(l0 + CLEN, a0n, a1n);   // prefetch chunk 2 (lands under scan)
    ldB(l0 + CLEN, Bvn);
    dma_x(l0 + CLEN);
    scanloc(c0);
    wait_vm0();
    __syncthreads();

    pack(a0n, a1n, Bvn);
    __syncthreads();
    scanloc(c0 + 1);
}

// Prefix-compose (P,S) over chunks -> H0[c] = h entering chunk c.
__global__ __launch_bounds__(256) void compose_k(const float* __restrict__ P,
                                                 const float* __restrict__ S,
                                                 float* __restrict__ H0) {
    int idx = blockIdx.x * 256 + threadIdx.x;   // over BB*DI*DSTATE
    const size_t stride = (size_t)BB * DI * DSTATE;
    float h = 0.f;
    #pragma unroll
    for (int c = 0; c < NC; ++c) {
        H0[(size_t)c * stride + idx] = h;
        h = __builtin_fmaf(P[(size_t)c * stride + idx], h, S[(size_t)c * stride + idx]);
    }
}

// Phase 2: re-run local scan from H0 (h carried in-register across the block's
// two chunks), emit y (D-skip + gate fused via ssk pack).
__global__ __launch_bounds__(256) void scan2_k(const bf16* __restrict__ dtb,
                                               const bf16* __restrict__ wdt,
                                               const float* __restrict__ dtbias,
                                               const bf16* __restrict__ xcb,
                                               const bf16* __restrict__ gzb,
                                               const float* __restrict__ xdbl,
                                               const float* __restrict__ A_log,
                                               const float* __restrict__ Dskip,
                                               const float* __restrict__ H0buf,
                                               bf16* __restrict__ ybf) {
    const int b   = blockIdx.y;
    const int d0  = blockIdx.x * 16;
    const int c0  = blockIdx.z * 2;
    const int tid = threadIdx.x;
    const int dl  = tid >> 4;
    const int n   = tid & 15;
    const int wv  = tid >> 6;
    const int lane = tid & 63;
    const int lr  = lane & 15;
    const int q   = lane >> 4;

    const float a2  = -__expf(A_log[(size_t)(d0 + dl) * DSTATE + n]) * LOG2E;
    const float bi  = dtbias[d0 + lr];
    const float dsk = Dskip[d0 + lr];

    __shared__ __align__(16) bf16   sxc[CLEN][16];
    __shared__ __align__(16) bf16   sgz[CLEN][16];
    __shared__ __align__(16) float  sdpT[16][TROW];
    __shared__ __align__(16) float  sbcT[16][TROW];
    __shared__ __align__(16) float2 ssk[CLEN][16];   // (xc*Dskip, gz)
    __shared__ __align__(16) float  syT[16][SYROW];

    const bf16x8 wf0 = *(const bf16x8*)&wdt[(size_t)(d0 + lr) * DTPAD + q * 8];
    const bf16x8 wf1 = *(const bf16x8*)&wdt[(size_t)(d0 + lr) * DTPAD + 32 + q * 8];

    auto ldA = [&](int l0, bf16x8& a0, bf16x8& a1) {
        const bf16* r = &dtb[(size_t)(b * LL + l0 + 16 * wv + lr) * DTPAD + q * 8];
        a0 = *(const bf16x8*)r;
        a1 = *(const bf16x8*)(r + 32);
    };
    auto ldBC = [&](int l0, float* Bv, float* Cv) {
        #pragma unroll
        for (int k2 = 0; k2 < 4; ++k2) {
            int ii = (tid + 256 * k2) >> 4;
            const float* p = &xdbl[(size_t)(b * LL + l0 + ii) * NXP + DTRANK + n];
            Bv[k2] = p[0];
            Cv[k2] = p[DSTATE];
        }
    };
    auto dma_xg = [&](int l0) {
        if (tid < 128) {
            int r2 = tid >> 1, c2 = tid & 1;
            ld16((char*)&sxc[0][0] + (tid & ~63) * 16,
                 xcb + (size_t)(b * LL + l0 + r2) * DI + d0 + c2 * 8);
        } else {
            int t2 = tid - 128, r2 = t2 >> 1, c2 = t2 & 1;
            ld16((char*)&sgz[0][0] + (t2 & ~63) * 16,
                 gzb + (size_t)(b * LL + l0 + r2) * DI + d0 + c2 * 8);
        }
    };
    auto pack = [&](bf16x8 a0, bf16x8 a1, const float* Bv, const float* Cv) {
        floatx4 dacc = (floatx4){0.f, 0.f, 0.f, 0.f};
        dacc = __builtin_amdgcn_mfma_f32_16x16x32_bf16(a0, wf0, dacc, 0, 0, 0);
        dacc = __builtin_amdgcn_mfma_f32_16x16x32_bf16(a1, wf1, dacc, 0, 0, 0);
        float vv[4], xvv[4];
        #pragma unroll
        for (int r = 0; r < 4; ++r) {
            int l = 16 * wv + q * 4 + r;
            float v = dacc[r] + bi;
            v = (v > 20.f) ? v : log1pf(__expf(v));
            vv[r] = v; xvv[r] = (float)sxc[l][lr];
            float gv = (float)sgz[l][lr];
            ssk[l][lr] = make_float2(xvv[r] * dsk, gv);
        }
        int L0 = 16 * wv + q * 4;
        *(float4*)&sdpT[lr][2 * L0] =
            make_float4(vv[0], vv[0] * xvv[0], vv[1], vv[1] * xvv[1]);
        *(float4*)&sdpT[lr][2 * L0 + 4] =
            make_float4(vv[2], vv[2] * xvv[2], vv[3], vv[3] * xvv[3]);
        #pragma unroll
        for (int k2 = 0; k2 < 4; ++k2) {
            int ii = (tid + 256 * k2) >> 4;
            *(float2*)&sbcT[n][2 * ii] = make_float2(Bv[k2], Cv[k2]);
        }
    };
    auto scan64 = [&](float& h) {
        const float4* dpr = (const float4*)&sdpT[dl][0];
        const float4* bcr = (const float4*)&sbcT[n][0];
        float4 dA[4], bA[4], dB2[4], bB2[4];
        float y4[4];
        #pragma unroll
        for (int t = 0; t < 4; ++t) { dA[t] = dpr[t]; bA[t] = bcr[t]; }
        #pragma unroll
        for (int g = 0; g < 8; ++g) {
            #pragma unroll
            for (int t = 0; t < 4; ++t) {
                if (g + 1 < 8) {
                    if ((g & 1) == 0) { dB2[t] = dpr[(g + 1) * 4 + t]; bB2[t] = bcr[(g + 1) * 4 + t]; }
                    else              { dA[t]  = dpr[(g + 1) * 4 + t]; bA[t]  = bcr[(g + 1) * 4 + t]; }
                }
            }
            #pragma unroll
            for (int i = 0; i < 8; ++i) {
                float4 v = ((g & 1) == 0) ? dA[i >> 1] : dB2[i >> 1];
                float4 w = ((g & 1) == 0) ? bA[i >> 1] : bB2[i >> 1];
                float dvx = (i & 1) ? v.z : v.x;
                float dpy = (i & 1) ? v.w : v.y;
                float bx  = (i & 1) ? w.z : w.x;
                float cy  = (i & 1) ? w.w : w.y;
                float e = exp2_raw(dvx * a2);
                h = __builtin_fmaf(e, h, dpy * bx);
                y4[i & 3] = row16_sum(h * cy);
                if ((i & 3) == 3 && n == 0) {
                    *(floatx4*)&syT[dl][g * 8 + i - 3] =
                        (floatx4){y4[0], y4[1], y4[2], y4[3]};
                }
            }
        }
    };
    auto emit = [&](int l0) {
        #pragma unroll
        for (int k2 = 0; k2 < 4; ++k2) {
            int idx = tid + 256 * k2, ii = idx >> 4, dd = idx & 15;
            float2 sk = ssk[ii][dd];
            float yv = (syT[dd][ii] + sk.x) * sk.y;
            ybf[(size_t)(b * LL + l0 + ii) * DI + d0 + dd] = (bf16)yv;
        }
    };

    const int l0 = c0 * CLEN;
    float h = H0buf[((size_t)c0 * BB + b) * (DI * DSTATE) + (size_t)(d0 + dl) * DSTATE + n];

    bf16x8 a0, a1, a0n, a1n;
    float Bv[4], Cv[4], Bvn[4], Cvn[4];

    ldA(l0, a0, a1);
    ldBC(l0, Bv, Cv);
    dma_xg(l0);
    wait_vm0();
    __syncthreads();

    pack(a0, a1, Bv, Cv);
    __syncthreads();
    ldA(l0 + CLEN, a0n, a1n);   // prefetch chunk 2 (lands under scan)
    ldBC(l0 + CLEN, Bvn, Cvn);
    dma_xg(l0 + CLEN);
    scan64(h);
    __syncthreads();            // syT visible
    wait_vm0();                 // chunk-2 staging landed
    emit(l0);
    __syncthreads();            // ssk/sxc/sgz safe to reuse

    pack(a0n, a1n, Bvn, Cvn);
    __syncthreads();
    scan64(h);                  // h carried: continuation == reference order
    __syncthreads();
    emit(l0 + CLEN);
}

// ---------------------------------------------------------------- head
__global__ __launch_bounds__(256) void head_norm_k(const float* __restrict__ x,
                                                   const float* __restrict__ fnw,
                                                   float* __restrict__ xn_buf) {
    int b = blockIdx.x;
    int tid = threadIdx.x;
    const float* xr = x + ((size_t)b * LL + (LL - 1)) * DD;
    __shared__ float sred[4];
    float v[3]; float ss = 0.f;
    for (int j = 0; j < 3; j++) { v[j] = xr[tid + j * 256]; ss += v[j] * v[j]; }
    for (int o = 1; o < 64; o <<= 1) ss += __shfl_xor(ss, o, 64);
    if ((tid & 63) == 0) sred[tid >> 6] = ss;
    __syncthreads();
    float scale = rsqrtf((sred[0] + sred[1] + sred[2] + sred[3]) / (float)DD + 1e-6f);
    for (int j = 0; j < 3; j++) {
        int c = tid + j * 256;
        xn_buf[(size_t)b * DD + c] = v[j] * scale * fnw[c];
    }
}

__global__ __launch_bounds__(256) void head_h1_k(const float* __restrict__ xn_buf,
                                                 const float* __restrict__ h1w,
                                                 const float* __restrict__ h1b,
                                                 float* __restrict__ h_buf) {
    int b  = blockIdx.x;
    int o0 = blockIdx.y * 64;
    int tid = threadIdx.x;
    __shared__ float sx[DD];
    for (int c = tid; c < DD; c += 256) sx[c] = xn_buf[(size_t)b * DD + c];
    __syncthreads();
    int wave = tid >> 6, lane = tid & 63;
    for (int j = 0; j < 16; j++) {
        int o = o0 + wave * 16 + j;
        const float* wrow = h1w + (size_t)o * DD;
        float acc = 0.f;
        for (int k = 0; k < 12; k++) {
            int c = lane + 64 * k;
            acc += wrow[c] * sx[c];
        }
        for (int off = 1; off < 64; off <<= 1) acc += __shfl_xor(acc, off, 64);
        if (lane == 0) h_buf[(size_t)b * DD + o] = acc + h1b[o];
    }
}

__global__ __launch_bounds__(256) void head_out_k(const float* __restrict__ h_buf,
                                                  const float* __restrict__ hnw,
                                                  const float* __restrict__ h2w,
                                                  const float* __restrict__ h2b,
                                                  float* __restrict__ out) {
    int b = blockIdx.x;
    int tid = threadIdx.x;
    __shared__ float hh[DD];
    __shared__ float sred[4];
    const float* hr = h_buf + (size_t)b * DD;
    float ss = 0.f;
    for (int c = tid; c < DD; c += 256) { float v = hr[c]; ss += v * v; }
    for (int o = 1; o < 64; o <<= 1) ss += __shfl_xor(ss, o, 64);
    if ((tid & 63) == 0) sred[tid >> 6] = ss;
    __syncthreads();
    float sc = rsqrtf((sred[0] + sred[1] + sred[2] + sred[3]) / (float)DD + 1e-6f);
    for (int c = tid; c < DD; c += 256) {
        float v = hr[c] * sc * hnw[c];
        hh[c] = 0.5f * v * (1.f + erff(v * 0.70710678118f));
    }
    __syncthreads();
    int w = tid >> 6, lane = tid & 63;
    for (int j = w; j < 10; j += 4) {
        float acc = 0.f;
        const float* wrow = h2w + (size_t)j * DD;
        for (int c = lane; c < DD; c += 64) acc += hh[c] * wrow[c];
        for (int o = 1; o < 64; o <<= 1) acc += __shfl_xor(acc, o, 64);
        if (lane == 0) out[b * 10 + j] = acc + h2b[j];
    }
}

// ----------------------------------------------------------------
extern "C" void kernel_launch(void* const* d_in, const int* in_sizes, int n_in,
                              void* d_out, int out_size, void* d_ws, size_t ws_size,
                              hipStream_t stream) {
    const float* x_in      = (const float*)d_in[0];
    const float* norm_w    = (const float*)d_in[1];
    const float* in_proj_w = (const float*)d_in[2];
    const float* conv_w    = (const float*)d_in[3];
    const float* conv_b    = (const float*)d_in[4];
    const float* x_proj_w  = (const float*)d_in[5];
    const float* dt_proj_w = (const float*)d_in[6];
    const float* dt_proj_b = (const float*)d_in[7];
    const float* A_log     = (const float*)d_in[8];
    const float* D_skip    = (const float*)d_in[9];
    const float* out_proj_w= (const float*)d_in[10];
    const float* fnw       = (const float*)d_in[11];
    const float* h1w       = (const float*)d_in[12];
    const float* h1b       = (const float*)d_in[13];
    const float* hnw       = (const float*)d_in[14];
    const float* h2w       = (const float*)d_in[15];
    const float* h2b       = (const float*)d_in[16];
    float* out = (float*)d_out;

    char* ws = (char*)d_ws;
    size_t off = 0;
    auto alloc = [&](size_t bytes) -> void* {
        void* p = ws + off;
        off += (bytes + 255) & ~(size_t)255;
        return p;
    };
    bf16* w_in  = (bf16*)alloc((size_t)N1 * 2);
    bf16* w_xp  = (bf16*)alloc((size_t)N2 * 2);
    bf16* w_dt  = (bf16*)alloc((size_t)N3 * 2);
    bf16* w_out = (bf16*)alloc((size_t)N4 * 2);
    bf16* xn_bf = (bf16*)alloc((size_t)MROWS * DD * 2);
    bf16* xz_bf = (bf16*)alloc((size_t)MROWS * 2 * DI * 2);
    bf16* xc_bf = (bf16*)alloc((size_t)MROWS * DI * 2);
    bf16* gz_bf = (bf16*)alloc((size_t)MROWS * DI * 2);
    float* xdbl = (float*)alloc((size_t)MROWS * NXP * 4);
    bf16* dt_bf = (bf16*)alloc((size_t)MROWS * DTPAD * 2);
    bf16* y_bf  = (bf16*)alloc((size_t)MROWS * DI * 2);
    float* x_buf= (float*)alloc((size_t)MROWS * DD * 4);
    float* Pbuf = (float*)alloc((size_t)NC * BB * DI * DSTATE * 4);
    float* Sbuf = (float*)alloc((size_t)NC * BB * DI * DSTATE * 4);
    float* H0buf= (float*)alloc((size_t)NC * BB * DI * DSTATE * 4);
    float* xnl  = (float*)alloc((size_t)BB * DD * 4);
    float* hbuf = (float*)alloc((size_t)BB * DD * 4);
    float* xp_part = (float*)alloc((size_t)KSPLIT * MROWS * NXP * 4);
    float* op_part = (float*)alloc((size_t)OPKS * MROWS * DD * 4);

    // all weight conversions in one launch
    {
        int ntot = N1 + N2 + N3 + N4;
        cvt_all_k<<<(ntot + 255) / 256, 256, 0, stream>>>(
            in_proj_w, x_proj_w, dt_proj_w, out_proj_w, w_in, w_xp, w_dt, w_out);
    }

    for (int i = 0; i < 4; i++) {
        const float* x_src = (i == 0) ? x_in : x_buf;
        // 1. rmsnorm (layer 0 only; later layers get xn_bf from fused op_reduce_norm)
        if (i == 0)
            rmsnorm_k<<<MROWS, 256, 0, stream>>>(x_src, norm_w, xn_bf);
        // 2. in_proj: (2048 x 3072), bf16 out
        gemm_bt<1><<<dim3(MROWS / 128, 3072 / 128), 256, 0, stream>>>(
            xn_bf, w_in + (size_t)i * 3072 * 768, nullptr, xz_bf,
            MROWS, 2 * DI, DD);
        // 3. causal conv + silu + silu(z) gate (bf16 outputs)
        conv_silu_k<<<(MROWS * (DI / 4) + 255) / 256, 256, 0, stream>>>(
            xz_bf, conv_w + (size_t)i * DI * 4, conv_b + (size_t)i * DI, xc_bf, gz_bf);
        // 4. x_proj split-K + reduce -> xdbl f32 + padded bf16 dt
        gemm_xp<<<dim3(MROWS / 64, KSPLIT), 256, 0, stream>>>(
            xc_bf, w_xp + (size_t)i * NXP * DI, xp_part);
        xp_reduce_k<<<(MROWS * NXP + 255) / 256, 256, 0, stream>>>(xp_part, xdbl, dt_bf);
        // 5. chunk-parallel 2-phase scan (2 chunks/block, reg-staged operands)
        scan1_k<<<dim3(DI / 16, BB, NC / 2), 256, 0, stream>>>(
            dt_bf, w_dt + (size_t)i * DI * DTPAD, dt_proj_b + (size_t)i * DI,
            xc_bf, xdbl, A_log + (size_t)i * DI * DSTATE, Pbuf, Sbuf);
        compose_k<<<(BB * DI * DSTATE) / 256, 256, 0, stream>>>(Pbuf, Sbuf, H0buf);
        scan2_k<<<dim3(DI / 16, BB, NC / 2), 256, 0, stream>>>(
            dt_bf, w_dt + (size_t)i * DI * DTPAD, dt_proj_b + (size_t)i * DI,
            xc_bf, gz_bf, xdbl, A_log + (size_t)i * DI * DSTATE,
            D_skip + (size_t)i * DI, H0buf, y_bf);
        // 6. out_proj split-K -> partials; fused reduce + residual + next rmsnorm
        gemm_bt<5><<<dim3(MROWS / 128, DD / 128, OPKS), 256, 0, stream>>>(
            y_bf, w_out + (size_t)i * DD * DI, op_part, nullptr,
            MROWS, DD, DI);
        op_reduce_norm_k<<<MROWS, 256, 0, stream>>>(
            op_part, x_src, norm_w + ((i + 1) & 3) * DD, x_buf, xn_bf);
    }

    head_norm_k<<<BB, 256, 0, stream>>>(x_buf, fnw, xnl);
    head_h1_k<<<dim3(BB, DD / 64), 256, 0, stream>>>(xnl, h1w, h1b, hbuf);
    head_out_k<<<BB, 256, 0, stream>>>(hbuf, hnw, h2w, h2b, out);
}

// Round 6
// 660.260 us; speedup vs baseline: 1.0160x; 1.0160x over previous
//
#include <hip/hip_runtime.h>
#include <hip/hip_bf16.h>
#include <math.h>

typedef __bf16 bf16;
typedef __bf16 bf16x4 __attribute__((ext_vector_type(4)));
typedef __bf16 bf16x8 __attribute__((ext_vector_type(8)));
typedef float floatx4 __attribute__((ext_vector_type(4)));

#define BB 2
#define LL 1024
#define DD 768
#define DI 1536
#define MROWS 2048   // B*L
#define NXP 80       // dt_rank + 2*d_state
#define DTRANK 48
#define DTPAD 64     // dt K padded to 64
#define DSTATE 16
#define NC 16        // scan chunks
#define CLEN 64      // scan chunk length (NC*CLEN == LL)
#define KSPLIT 16    // x_proj split-K factor (K-seg = 96)
#define OPKS 4       // out_proj split-K factor (K-seg = 384)
#define LOG2E 1.4426950408889634f
#define TROW 132     // floats per sdpT/sbcT row (128 data + 4 pad)
#define SYROW 68     // floats per syT/sST row

// async global->LDS, 16 B per lane; lds dest must be wave-uniform base (+lane*16)
__device__ __forceinline__ void ld16(void* lds, const void* g) {
    __builtin_amdgcn_global_load_lds(
        (const __attribute__((address_space(1))) void*)g,
        (__attribute__((address_space(3))) void*)lds, 16, 0, 0);
}

// drain this wave's outstanding async global_load_lds before signalling barrier.
__device__ __forceinline__ void wait_vm0() {
    asm volatile("s_waitcnt vmcnt(0)" ::: "memory");
}

// DPP row-reduce over 16 lanes (one DPP row): lane 0 of each row gets the sum.
__device__ __forceinline__ float row16_sum(float x) {
    float t;
    t = __int_as_float(__builtin_amdgcn_update_dpp(0, __float_as_int(x), 0x111, 0xF, 0xF, true)); x += t;
    t = __int_as_float(__builtin_amdgcn_update_dpp(0, __float_as_int(x), 0x112, 0xF, 0xF, true)); x += t;
    t = __int_as_float(__builtin_amdgcn_update_dpp(0, __float_as_int(x), 0x114, 0xF, 0xF, true)); x += t;
    t = __int_as_float(__builtin_amdgcn_update_dpp(0, __float_as_int(x), 0x118, 0xF, 0xF, true)); x += t;
    return x;
}

// raw v_exp_f32 (no ocml denormal fixup; exp2(x<-126) flushes to 0 which is fine here)
__device__ __forceinline__ float exp2_raw(float x) {
#if __has_builtin(__builtin_amdgcn_exp2f)
    return __builtin_amdgcn_exp2f(x);
#else
    float r; asm("v_exp_f32 %0, %1" : "=v"(r) : "v"(x)); return r;
#endif
}

// ---------------------------------------------------------------- all weight cvt in one kernel
#define N1 (4 * 3072 * 768)
#define N2 (4 * NXP * DI)
#define N3 (4 * DI * DTPAD)
#define N4 (4 * DD * DI)
#define N5 (4 * DSTATE * DI)   // a2T[layer][n][d] = -exp(A_log[layer,d,n])*log2(e)
__global__ __launch_bounds__(256) void cvt_all_k(const float* __restrict__ in_proj_w,
                                                 const float* __restrict__ x_proj_w,
                                                 const float* __restrict__ dt_proj_w,
                                                 const float* __restrict__ out_proj_w,
                                                 const float* __restrict__ A_log,
                                                 bf16* __restrict__ w_in,
                                                 bf16* __restrict__ w_xp,
                                                 bf16* __restrict__ w_dt,
                                                 bf16* __restrict__ w_out,
                                                 float* __restrict__ a2T) {
    int i = blockIdx.x * 256 + threadIdx.x;
    if (i < N1) { w_in[i] = (bf16)in_proj_w[i]; return; }
    i -= N1;
    if (i < N2) { w_xp[i] = (bf16)x_proj_w[i]; return; }
    i -= N2;
    if (i < N3) {
        int row = i >> 6, c = i & 63;
        w_dt[i] = (c < DTRANK) ? (bf16)dt_proj_w[row * DTRANK + c] : (bf16)0.f;
        return;
    }
    i -= N3;
    if (i < N4) { w_out[i] = (bf16)out_proj_w[i]; return; }
    i -= N4;
    if (i < N5) {
        int layer = i / (DSTATE * DI);
        int rem   = i - layer * (DSTATE * DI);
        int n     = rem / DI;
        int d     = rem - n * DI;
        a2T[i] = -__expf(A_log[(size_t)layer * DI * DSTATE + d * DSTATE + n]) * LOG2E;
    }
}

// ---------------------------------------------------------------- rmsnorm -> bf16 (layer 0 only)
__global__ __launch_bounds__(256) void rmsnorm_k(const float* __restrict__ x,
                                                 const float* __restrict__ w,
                                                 bf16* __restrict__ out) {
    int row = blockIdx.x;
    const float* xr = x + (size_t)row * DD;
    int tid = threadIdx.x;
    float v[3]; float ss = 0.f;
    for (int j = 0; j < 3; j++) { v[j] = xr[tid + j * 256]; ss += v[j] * v[j]; }
    for (int o = 1; o < 64; o <<= 1) ss += __shfl_xor(ss, o, 64);
    __shared__ float sred[4];
    if ((tid & 63) == 0) sred[tid >> 6] = ss;
    __syncthreads();
    float scale = rsqrtf((sred[0] + sred[1] + sred[2] + sred[3]) / (float)DD + 1e-6f);
    for (int j = 0; j < 3; j++) {
        int c = tid + j * 256;
        out[(size_t)row * DD + c] = (bf16)(v[j] * scale * w[c]);
    }
}

// ---------------------------------------------------------------- GEMM: C = A @ W^T
// MODE 1: store bf16 | MODE 5: split-K partials f32
template <int MODE>
__global__ __launch_bounds__(256) void gemm_bt(const bf16* __restrict__ A,
                                               const bf16* __restrict__ W,
                                               float* __restrict__ Cf,
                                               bf16* __restrict__ Cb,
                                               int M, int N, int K) {
    __shared__ bf16 As[128][32];
    __shared__ bf16 Ws[128][32];
    const int tid  = threadIdx.x;
    const int m0   = blockIdx.x * 128;
    const int n0   = blockIdx.y * 128;
    const int wave = tid >> 6;
    const int lane = tid & 63;
    const int wm   = (wave >> 1) * 64;
    const int wn   = (wave & 1) * 64;
    const int lrow = lane & 15;
    const int quad = lane >> 4;

    int kbeg = 0, kend = K;
    if constexpr (MODE == 5) {
        int kseg = K / gridDim.z;
        kbeg = blockIdx.z * kseg;
        kend = kbeg + kseg;
        Cf  += (size_t)blockIdx.z * M * N;
    }

    floatx4 acc[4][4];
    for (int mi = 0; mi < 4; mi++)
        for (int ni = 0; ni < 4; ni++) acc[mi][ni] = (floatx4){0.f, 0.f, 0.f, 0.f};

    const int r0  = tid >> 2;        // 0..63
    const int r1  = r0 + 64;         // 64..127
    const int seg = (tid & 3) * 8;   // 0,8,16,24
    char* asb0 = (char*)As + wave * 1024;
    char* asb1 = (char*)As + 4096 + wave * 1024;
    char* wsb0 = (char*)Ws + wave * 1024;
    char* wsb1 = (char*)Ws + 4096 + wave * 1024;

    for (int kb = kbeg; kb < kend; kb += 32) {
        int gk = kb + seg;
        __syncthreads();   // previous iteration's LDS reads done
        ld16(asb0, A + (size_t)(m0 + r0) * K + gk);
        ld16(asb1, A + (size_t)(m0 + r1) * K + gk);
        ld16(wsb0, W + (size_t)(n0 + r0) * K + gk);
        ld16(wsb1, W + (size_t)(n0 + r1) * K + gk);
        wait_vm0();        // this wave's async LDS fills landed
        __syncthreads();   // all waves' fills landed -> tiles ready
        bf16x8 af[4], wf[4];
        for (int mi = 0; mi < 4; mi++) af[mi] = *(const bf16x8*)&As[wm + mi * 16 + lrow][quad * 8];
        for (int ni = 0; ni < 4; ni++) wf[ni] = *(const bf16x8*)&Ws[wn + ni * 16 + lrow][quad * 8];
        for (int mi = 0; mi < 4; mi++)
            for (int ni = 0; ni < 4; ni++)
                acc[mi][ni] = __builtin_amdgcn_mfma_f32_16x16x32_bf16(af[mi], wf[ni], acc[mi][ni], 0, 0, 0);
    }
    for (int mi = 0; mi < 4; mi++) {
        int rowb = m0 + wm + mi * 16 + quad * 4;
        for (int ni = 0; ni < 4; ni++) {
            int col = n0 + wn + ni * 16 + lrow;
            for (int r = 0; r < 4; r++) {
                int row = rowb + r;
                float v = acc[mi][ni][r];
                if constexpr (MODE == 1) Cb[(size_t)row * N + col] = (bf16)v;
                else                     Cf[(size_t)row * N + col] = v;
            }
        }
    }
}

// ---------------------------------------------------------------- out_proj partials + residual + NEXT layer rmsnorm (fused)
__global__ __launch_bounds__(256) void op_reduce_norm_k(const float* __restrict__ part,
                                                        const float* __restrict__ resid,
                                                        const float* __restrict__ nw,
                                                        float* __restrict__ xout,
                                                        bf16* __restrict__ xnb) {
    int row = blockIdx.x;
    int tid = threadIdx.x;
    float v[3]; float ss = 0.f;
    for (int j = 0; j < 3; j++) {
        int c = tid + j * 256;
        size_t idx = (size_t)row * DD + c;
        float s = resid[idx];
        for (int ks = 0; ks < OPKS; ks++) s += part[(size_t)ks * MROWS * DD + idx];
        v[j] = s;
        xout[idx] = s;
        ss += s * s;
    }
    for (int o = 1; o < 64; o <<= 1) ss += __shfl_xor(ss, o, 64);
    __shared__ float sred[4];
    if ((tid & 63) == 0) sred[tid >> 6] = ss;
    __syncthreads();
    float scale = rsqrtf((sred[0] + sred[1] + sred[2] + sred[3]) / (float)DD + 1e-6f);
    for (int j = 0; j < 3; j++) {
        int c = tid + j * 256;
        xnb[(size_t)row * DD + c] = (bf16)(v[j] * scale * nw[c]);
    }
}

// ---------------------------------------------------------------- x_proj split-K GEMM
__global__ __launch_bounds__(256) void gemm_xp(const bf16* __restrict__ A,
                                               const bf16* __restrict__ W,
                                               float* __restrict__ part) {
    __shared__ bf16 As[64][40];
    __shared__ bf16 Ws[128][40];
    const int tid  = threadIdx.x;
    const int m0   = blockIdx.x * 64;
    const int ks   = blockIdx.y;
    const int k0   = ks * (DI / KSPLIT);
    const int wave = tid >> 6;
    const int lane = tid & 63;
    const int lrow = lane & 15;
    const int quad = lane >> 4;
    const int wm   = wave * 16;

    floatx4 acc[5];
    for (int ni = 0; ni < 5; ni++) acc[ni] = (floatx4){0.f, 0.f, 0.f, 0.f};

    const int ra  = tid >> 2;
    const int rw1 = ra + 64;
    const int seg = (tid & 3) * 8;

    for (int kb = 0; kb < DI / KSPLIT; kb += 32) {
        int gk = k0 + kb + seg;
        bf16x8 va = *(const bf16x8*)(A + (size_t)(m0 + ra) * DI + gk);
        bf16x8 vw0, vw1;
        if (ra < NXP) vw0 = *(const bf16x8*)(W + (size_t)ra * DI + gk);
        else          for (int j = 0; j < 8; j++) vw0[j] = (bf16)0.f;
        if (rw1 < NXP) vw1 = *(const bf16x8*)(W + (size_t)rw1 * DI + gk);
        else           for (int j = 0; j < 8; j++) vw1[j] = (bf16)0.f;
        __syncthreads();
        *(bf16x8*)&As[ra][seg]  = va;
        *(bf16x8*)&Ws[ra][seg]  = vw0;
        *(bf16x8*)&Ws[rw1][seg] = vw1;
        __syncthreads();
        bf16x8 af = *(const bf16x8*)&As[wm + lrow][quad * 8];
        for (int ni = 0; ni < 5; ni++) {
            bf16x8 wf = *(const bf16x8*)&Ws[ni * 16 + lrow][quad * 8];
            acc[ni] = __builtin_amdgcn_mfma_f32_16x16x32_bf16(af, wf, acc[ni], 0, 0, 0);
        }
    }
    float* pout = part + (size_t)ks * MROWS * NXP;
    for (int ni = 0; ni < 5; ni++) {
        int col = ni * 16 + lrow;
        for (int r = 0; r < 4; r++) {
            int row = m0 + wm + quad * 4 + r;
            pout[(size_t)row * NXP + col] = acc[ni][r];
        }
    }
}

// reduce split-K partials -> xdbl f32 + padded bf16 dt
__global__ __launch_bounds__(256) void xp_reduce_k(const float* __restrict__ part,
                                                   float* __restrict__ xdbl,
                                                   bf16* __restrict__ dtbf) {
    int idx = blockIdx.x * 256 + threadIdx.x;
    if (idx >= MROWS * NXP) return;
    float s = 0.f;
    for (int j = 0; j < KSPLIT; j++) s += part[(size_t)j * MROWS * NXP + idx];
    xdbl[idx] = s;
    int m = idx / NXP, c = idx - m * NXP;
    if (c < DTRANK)      dtbf[m * DTPAD + c] = (bf16)s;
    else if (c < DTPAD)  dtbf[m * DTPAD + c] = (bf16)0.f;
}

// ---------------------------------------------------------------- causal depthwise conv + silu + gate (4-wide, bf16 outputs)
__global__ __launch_bounds__(256) void conv_silu_k(const bf16* __restrict__ xz,
                                                   const float* __restrict__ cw,
                                                   const float* __restrict__ cb,
                                                   bf16* __restrict__ xcb,
                                                   bf16* __restrict__ gzb) {
    int t = blockIdx.x * 256 + threadIdx.x;
    if (t >= MROWS * (DI / 4)) return;
    int m = t / (DI / 4);
    int d = (t - m * (DI / 4)) * 4;
    int l = m & (LL - 1);
    float acc[4];
    floatx4 cwv[4];
    for (int q = 0; q < 4; q++) {
        acc[q] = cb[d + q];
        cwv[q] = *(const floatx4*)&cw[(d + q) * 4];
    }
    for (int k = 0; k < 4; k++) {
        int lp = l - 3 + k;
        if (lp >= 0) {
            bf16x4 v = *(const bf16x4*)&xz[(size_t)(m - 3 + k) * (2 * DI) + d];
            for (int q = 0; q < 4; q++) acc[q] += (float)v[q] * cwv[q][k];
        }
    }
    bf16x4 xo, go;
    bf16x4 z4 = *(const bf16x4*)&xz[(size_t)m * (2 * DI) + DI + d];
    for (int q = 0; q < 4; q++) {
        float s = acc[q] / (1.f + __expf(-acc[q]));
        xo[q] = (bf16)s;
        float zv = (float)z4[q];
        go[q] = (bf16)(zv / (1.f + __expf(-zv)));
    }
    *(bf16x4*)&xcb[(size_t)m * DI + d] = xo;
    *(bf16x4*)&gzb[(size_t)m * DI + d] = go;
}

// ---------------------------------------------------------------- selective scan v6: single serial pass + parallel correction
// Exact identity: within a chunk, h[l] = exp2(a2*Scum[l])*h0 + hloc[l], where
// hloc is the scan from 0 and Scum = cumsum(dv). Hence
//   y[l,d] = yloc[l,d] + sum_n C[l,n]*exp2(a2[d,n]*Scum[l,d])*h0[n].
// scanA: one local scan per chunk emitting yloc, Scum, and chunk (P,S) — the
// serial recurrence is paid ONCE (v5 paid it twice: scan1 + scan2 recompute).
// compose: prefix over chunks -> h0 (transposed [n][d] for corr float4 loads).
// corr: embarrassingly parallel correction + D-skip + gate -> y bf16. No serial
// chain, no DPP; runs at full occupancy.
__global__ __launch_bounds__(256) void scanA_k(const bf16* __restrict__ dtb,
                                               const bf16* __restrict__ wdt,
                                               const float* __restrict__ dtbias,
                                               const bf16* __restrict__ xcb,
                                               const float* __restrict__ xdbl,
                                               const float* __restrict__ A_log,
                                               float* __restrict__ Pbuf,
                                               float* __restrict__ Sbuf,
                                               float* __restrict__ ylbuf,
                                               float* __restrict__ scbuf) {
    const int b   = blockIdx.y;
    const int d0  = blockIdx.x * 16;
    const int c0  = blockIdx.z * 2;
    const int tid = threadIdx.x;
    const int dl  = tid >> 4;
    const int n   = tid & 15;
    const int wv  = tid >> 6;
    const int lane = tid & 63;
    const int lr  = lane & 15;
    const int q   = lane >> 4;

    const float a2 = -__expf(A_log[(size_t)(d0 + dl) * DSTATE + n]) * LOG2E;
    const float bi = dtbias[d0 + lr];

    __shared__ __align__(16) bf16  sxc[CLEN][16];   // conv out (DMA)
    __shared__ __align__(16) float sdpT[16][TROW];  // [d][2i]=(dv), [2i+1]=(dv*xc)
    __shared__ __align__(16) float sbcT[16][TROW];  // [n][2i]=(B), [2i+1]=(C)
    __shared__ __align__(16) float syT[16][SYROW];  // [d][i] yloc
    __shared__ __align__(16) float sST[16][SYROW];  // [d][i] Scum

    const bf16x8 wf0 = *(const bf16x8*)&wdt[(size_t)(d0 + lr) * DTPAD + q * 8];
    const bf16x8 wf1 = *(const bf16x8*)&wdt[(size_t)(d0 + lr) * DTPAD + 32 + q * 8];

    auto ldA = [&](int l0, bf16x8& a0, bf16x8& a1) {
        const bf16* r = &dtb[(size_t)(b * LL + l0 + 16 * wv + lr) * DTPAD + q * 8];
        a0 = *(const bf16x8*)r;
        a1 = *(const bf16x8*)(r + 32);
    };
    auto ldBC = [&](int l0, float* Bv, float* Cv) {
        #pragma unroll
        for (int k2 = 0; k2 < 4; ++k2) {
            int ii = (tid + 256 * k2) >> 4;
            const float* p = &xdbl[(size_t)(b * LL + l0 + ii) * NXP + DTRANK + n];
            Bv[k2] = p[0];
            Cv[k2] = p[DSTATE];
        }
    };
    auto dma_x = [&](int l0) {
        if (tid < 128) {
            int r2 = tid >> 1, c2 = tid & 1;
            ld16((char*)&sxc[0][0] + (tid & ~63) * 16,
                 xcb + (size_t)(b * LL + l0 + r2) * DI + d0 + c2 * 8);
        }
    };
    auto pack = [&](bf16x8 a0, bf16x8 a1, const float* Bv, const float* Cv) {
        floatx4 dacc = (floatx4){0.f, 0.f, 0.f, 0.f};
        dacc = __builtin_amdgcn_mfma_f32_16x16x32_bf16(a0, wf0, dacc, 0, 0, 0);
        dacc = __builtin_amdgcn_mfma_f32_16x16x32_bf16(a1, wf1, dacc, 0, 0, 0);
        float vv[4], xvv[4];
        #pragma unroll
        for (int r = 0; r < 4; ++r) {
            int l = 16 * wv + q * 4 + r;
            float v = dacc[r] + bi;
            v = (v > 20.f) ? v : log1pf(__expf(v));
            vv[r] = v; xvv[r] = (float)sxc[l][lr];
        }
        int L0 = 16 * wv + q * 4;
        *(float4*)&sdpT[lr][2 * L0] =
            make_float4(vv[0], vv[0] * xvv[0], vv[1], vv[1] * xvv[1]);
        *(float4*)&sdpT[lr][2 * L0 + 4] =
            make_float4(vv[2], vv[2] * xvv[2], vv[3], vv[3] * xvv[3]);
        #pragma unroll
        for (int k2 = 0; k2 < 4; ++k2) {
            int ii = (tid + 256 * k2) >> 4;
            *(float2*)&sbcT[n][2 * ii] = make_float2(Bv[k2], Cv[k2]);
        }
    };
    auto scan_loc = [&](int c) {
        float h = 0.f, sdc = 0.f;
        const float4* dpr = (const float4*)&sdpT[dl][0];
        const float4* bcr = (const float4*)&sbcT[n][0];
        float4 dA[4], bA[4], dB2[4], bB2[4];
        float y4[4], s4[4];
        #pragma unroll
        for (int t = 0; t < 4; ++t) { dA[t] = dpr[t]; bA[t] = bcr[t]; }
        #pragma unroll
        for (int g = 0; g < 8; ++g) {
            #pragma unroll
            for (int t = 0; t < 4; ++t) {
                if (g + 1 < 8) {
                    if ((g & 1) == 0) { dB2[t] = dpr[(g + 1) * 4 + t]; bB2[t] = bcr[(g + 1) * 4 + t]; }
                    else              { dA[t]  = dpr[(g + 1) * 4 + t]; bA[t]  = bcr[(g + 1) * 4 + t]; }
                }
            }
            #pragma unroll
            for (int i = 0; i < 8; ++i) {
                float4 v = ((g & 1) == 0) ? dA[i >> 1] : dB2[i >> 1];
                float4 w = ((g & 1) == 0) ? bA[i >> 1] : bB2[i >> 1];
                float dvx = (i & 1) ? v.z : v.x;
                float dpy = (i & 1) ? v.w : v.y;
                float bx  = (i & 1) ? w.z : w.x;
                float cy  = (i & 1) ? w.w : w.y;
                float e = exp2_raw(dvx * a2);
                h = __builtin_fmaf(e, h, dpy * bx);
                sdc += dvx;
                y4[i & 3] = row16_sum(h * cy);
                s4[i & 3] = sdc;
                if ((i & 3) == 3 && n == 0) {
                    *(floatx4*)&syT[dl][g * 8 + i - 3] =
                        (floatx4){y4[0], y4[1], y4[2], y4[3]};
                    *(floatx4*)&sST[dl][g * 8 + i - 3] =
                        (floatx4){s4[0], s4[1], s4[2], s4[3]};
                }
            }
        }
        size_t o = (((size_t)c * BB + b) * DI + (d0 + dl)) * DSTATE + n;
        Pbuf[o] = exp2_raw(a2 * sdc);
        Sbuf[o] = h;
    };
    auto emit = [&](int l0) {
        #pragma unroll
        for (int k2 = 0; k2 < 4; ++k2) {
            int idx = tid + 256 * k2, ii = idx >> 4, dd = idx & 15;
            size_t go = (size_t)(b * LL + l0 + ii) * DI + d0 + dd;
            ylbuf[go] = syT[dd][ii];
            scbuf[go] = sST[dd][ii];
        }
    };

    const int l0 = c0 * CLEN;
    bf16x8 a0, a1, a0n, a1n;
    float Bv[4], Cv[4], Bvn[4], Cvn[4];

    ldA(l0, a0, a1);
    ldBC(l0, Bv, Cv);
    dma_x(l0);
    wait_vm0();
    __syncthreads();

    pack(a0, a1, Bv, Cv);
    __syncthreads();
    ldA(l0 + CLEN, a0n, a1n);   // prefetch chunk 2 (lands under scan)
    ldBC(l0 + CLEN, Bvn, Cvn);
    dma_x(l0 + CLEN);
    scan_loc(c0);
    __syncthreads();            // syT/sST visible
    wait_vm0();                 // chunk-2 sxc DMA landed
    emit(l0);
    __syncthreads();            // packed bufs safe to overwrite

    pack(a0n, a1n, Bvn, Cvn);
    __syncthreads();
    scan_loc(c0 + 1);
    __syncthreads();
    emit(l0 + CLEN);
}

// Prefix-compose (P,S) over chunks -> H0T[c][n][d] = h entering chunk c (transposed).
__global__ __launch_bounds__(256) void compose_k(const float* __restrict__ P,
                                                 const float* __restrict__ S,
                                                 float* __restrict__ H0T) {
    int idx = blockIdx.x * 256 + threadIdx.x;   // over BB*DI*DSTATE, (b,d,n) order
    const size_t stride = (size_t)BB * DI * DSTATE;
    int b = idx / (DI * DSTATE);
    int rest = idx - b * (DI * DSTATE);
    int d = rest >> 4;
    int n = rest & 15;
    float h = 0.f;
    #pragma unroll
    for (int c = 0; c < NC; ++c) {
        H0T[((size_t)c * BB + b) * (DSTATE * DI) + (size_t)n * DI + d] = h;
        h = __builtin_fmaf(P[(size_t)c * stride + idx], h, S[(size_t)c * stride + idx]);
    }
}

// Parallel correction: y = (yloc + sum_n C*exp2(a2*Scum)*h0 + xc*D) * gz.
// grid (24, BB, NC); thread handles 4 l's (stride 16 in chunk) x 4 consecutive d.
__global__ __launch_bounds__(256) void corr_k(const float* __restrict__ ylbuf,
                                              const float* __restrict__ scbuf,
                                              const float* __restrict__ xdbl,
                                              const float* __restrict__ H0T,
                                              const float* __restrict__ a2T,
                                              const bf16* __restrict__ xcb,
                                              const bf16* __restrict__ gzb,
                                              const float* __restrict__ Dskip,
                                              bf16* __restrict__ ybf) {
    const int b = blockIdx.y, c = blockIdx.z;
    const int tid = threadIdx.x;
    const int t6 = blockIdx.x * 256 + tid;        // 0..6143
    const int dq   = (t6 % 384) * 4;              // d quad
    const int loff = t6 / 384;                    // 0..15

    __shared__ __align__(16) float sC[CLEN][16];  // C tile (d-independent)
    {
        int l = tid >> 2, nn = (tid & 3) * 4;
        *(float4*)&sC[l][nn] =
            *(const float4*)&xdbl[(size_t)(b * LL + c * CLEN + l) * NXP + DTRANK + DSTATE + nn];
    }
    __syncthreads();

    const float* h0base = H0T + ((size_t)c * BB + b) * (DSTATE * DI);
    int m0_ = b * LL + c * CLEN + loff;
    floatx4 acc[4];
    float4 sc[4];
    #pragma unroll
    for (int s = 0; s < 4; ++s) {
        size_t mo = (size_t)(m0_ + s * 16) * DI + dq;
        sc[s] = *(const float4*)&scbuf[mo];
        float4 yl = *(const float4*)&ylbuf[mo];
        acc[s] = (floatx4){yl.x, yl.y, yl.z, yl.w};
    }
    #pragma unroll
    for (int n = 0; n < DSTATE; ++n) {
        float4 a2v = *(const float4*)&a2T[(size_t)n * DI + dq];
        float4 h0v = *(const float4*)&h0base[(size_t)n * DI + dq];
        #pragma unroll
        for (int s = 0; s < 4; ++s) {
            float Cn = sC[loff + s * 16][n];
            acc[s][0] = __builtin_fmaf(Cn * h0v.x, exp2_raw(a2v.x * sc[s].x), acc[s][0]);
            acc[s][1] = __builtin_fmaf(Cn * h0v.y, exp2_raw(a2v.y * sc[s].y), acc[s][1]);
            acc[s][2] = __builtin_fmaf(Cn * h0v.z, exp2_raw(a2v.z * sc[s].z), acc[s][2]);
            acc[s][3] = __builtin_fmaf(Cn * h0v.w, exp2_raw(a2v.w * sc[s].w), acc[s][3]);
        }
    }
    float4 Dsk = *(const float4*)&Dskip[dq];
    #pragma unroll
    for (int s = 0; s < 4; ++s) {
        size_t mo = (size_t)(m0_ + s * 16) * DI + dq;
        bf16x4 xc4 = *(const bf16x4*)&xcb[mo];
        bf16x4 gz4 = *(const bf16x4*)&gzb[mo];
        bf16x4 yo;
        yo[0] = (bf16)((acc[s][0] + (float)xc4[0] * Dsk.x) * (float)gz4[0]);
        yo[1] = (bf16)((acc[s][1] + (float)xc4[1] * Dsk.y) * (float)gz4[1]);
        yo[2] = (bf16)((acc[s][2] + (float)xc4[2] * Dsk.z) * (float)gz4[2]);
        yo[3] = (bf16)((acc[s][3] + (float)xc4[3] * Dsk.w) * (float)gz4[3]);
        *(bf16x4*)&ybf[mo] = yo;
    }
}

// ---------------------------------------------------------------- head
__global__ __launch_bounds__(256) void head_norm_k(const float* __restrict__ x,
                                                   const float* __restrict__ fnw,
                                                   float* __restrict__ xn_buf) {
    int b = blockIdx.x;
    int tid = threadIdx.x;
    const float* xr = x + ((size_t)b * LL + (LL - 1)) * DD;
    __shared__ float sred[4];
    float v[3]; float ss = 0.f;
    for (int j = 0; j < 3; j++) { v[j] = xr[tid + j * 256]; ss += v[j] * v[j]; }
    for (int o = 1; o < 64; o <<= 1) ss += __shfl_xor(ss, o, 64);
    if ((tid & 63) == 0) sred[tid >> 6] = ss;
    __syncthreads();
    float scale = rsqrtf((sred[0] + sred[1] + sred[2] + sred[3]) / (float)DD + 1e-6f);
    for (int j = 0; j < 3; j++) {
        int c = tid + j * 256;
        xn_buf[(size_t)b * DD + c] = v[j] * scale * fnw[c];
    }
}

__global__ __launch_bounds__(256) void head_h1_k(const float* __restrict__ xn_buf,
                                                 const float* __restrict__ h1w,
                                                 const float* __restrict__ h1b,
                                                 float* __restrict__ h_buf) {
    int b  = blockIdx.x;
    int o0 = blockIdx.y * 64;
    int tid = threadIdx.x;
    __shared__ float sx[DD];
    for (int c = tid; c < DD; c += 256) sx[c] = xn_buf[(size_t)b * DD + c];
    __syncthreads();
    int wave = tid >> 6, lane = tid & 63;
    for (int j = 0; j < 16; j++) {
        int o = o0 + wave * 16 + j;
        const float* wrow = h1w + (size_t)o * DD;
        float acc = 0.f;
        for (int k = 0; k < 12; k++) {
            int c = lane + 64 * k;
            acc += wrow[c] * sx[c];
        }
        for (int off = 1; off < 64; off <<= 1) acc += __shfl_xor(acc, off, 64);
        if (lane == 0) h_buf[(size_t)b * DD + o] = acc + h1b[o];
    }
}

__global__ __launch_bounds__(256) void head_out_k(const float* __restrict__ h_buf,
                                                  const float* __restrict__ hnw,
                                                  const float* __restrict__ h2w,
                                                  const float* __restrict__ h2b,
                                                  float* __restrict__ out) {
    int b = blockIdx.x;
    int tid = threadIdx.x;
    __shared__ float hh[DD];
    __shared__ float sred[4];
    const float* hr = h_buf + (size_t)b * DD;
    float ss = 0.f;
    for (int c = tid; c < DD; c += 256) { float v = hr[c]; ss += v * v; }
    for (int o = 1; o < 64; o <<= 1) ss += __shfl_xor(ss, o, 64);
    if ((tid & 63) == 0) sred[tid >> 6] = ss;
    __syncthreads();
    float sc = rsqrtf((sred[0] + sred[1] + sred[2] + sred[3]) / (float)DD + 1e-6f);
    for (int c = tid; c < DD; c += 256) {
        float v = hr[c] * sc * hnw[c];
        hh[c] = 0.5f * v * (1.f + erff(v * 0.70710678118f));
    }
    __syncthreads();
    int w = tid >> 6, lane = tid & 63;
    for (int j = w; j < 10; j += 4) {
        float acc = 0.f;
        const float* wrow = h2w + (size_t)j * DD;
        for (int c = lane; c < DD; c += 64) acc += hh[c] * wrow[c];
        for (int o = 1; o < 64; o <<= 1) acc += __shfl_xor(acc, o, 64);
        if (lane == 0) out[b * 10 + j] = acc + h2b[j];
    }
}

// ----------------------------------------------------------------
extern "C" void kernel_launch(void* const* d_in, const int* in_sizes, int n_in,
                              void* d_out, int out_size, void* d_ws, size_t ws_size,
                              hipStream_t stream) {
    const float* x_in      = (const float*)d_in[0];
    const float* norm_w    = (const float*)d_in[1];
    const float* in_proj_w = (const float*)d_in[2];
    const float* conv_w    = (const float*)d_in[3];
    const float* conv_b    = (const float*)d_in[4];
    const float* x_proj_w  = (const float*)d_in[5];
    const float* dt_proj_w = (const float*)d_in[6];
    const float* dt_proj_b = (const float*)d_in[7];
    const float* A_log     = (const float*)d_in[8];
    const float* D_skip    = (const float*)d_in[9];
    const float* out_proj_w= (const float*)d_in[10];
    const float* fnw       = (const float*)d_in[11];
    const float* h1w       = (const float*)d_in[12];
    const float* h1b       = (const float*)d_in[13];
    const float* hnw       = (const float*)d_in[14];
    const float* h2w       = (const float*)d_in[15];
    const float* h2b       = (const float*)d_in[16];
    float* out = (float*)d_out;

    char* ws = (char*)d_ws;
    size_t off = 0;
    auto alloc = [&](size_t bytes) -> void* {
        void* p = ws + off;
        off += (bytes + 255) & ~(size_t)255;
        return p;
    };
    bf16* w_in  = (bf16*)alloc((size_t)N1 * 2);
    bf16* w_xp  = (bf16*)alloc((size_t)N2 * 2);
    bf16* w_dt  = (bf16*)alloc((size_t)N3 * 2);
    bf16* w_out = (bf16*)alloc((size_t)N4 * 2);
    float* a2T  = (float*)alloc((size_t)N5 * 4);
    bf16* xn_bf = (bf16*)alloc((size_t)MROWS * DD * 2);
    bf16* xz_bf = (bf16*)alloc((size_t)MROWS * 2 * DI * 2);
    bf16* xc_bf = (bf16*)alloc((size_t)MROWS * DI * 2);
    bf16* gz_bf = (bf16*)alloc((size_t)MROWS * DI * 2);
    float* xdbl = (float*)alloc((size_t)MROWS * NXP * 4);
    bf16* dt_bf = (bf16*)alloc((size_t)MROWS * DTPAD * 2);
    bf16* y_bf  = (bf16*)alloc((size_t)MROWS * DI * 2);
    float* x_buf= (float*)alloc((size_t)MROWS * DD * 4);
    float* Pbuf = (float*)alloc((size_t)NC * BB * DI * DSTATE * 4);
    float* Sbuf = (float*)alloc((size_t)NC * BB * DI * DSTATE * 4);
    float* H0T  = (float*)alloc((size_t)NC * BB * DI * DSTATE * 4);
    float* ylbuf= (float*)alloc((size_t)MROWS * DI * 4);
    float* scbuf= (float*)alloc((size_t)MROWS * DI * 4);
    float* xnl  = (float*)alloc((size_t)BB * DD * 4);
    float* hbuf = (float*)alloc((size_t)BB * DD * 4);
    float* xp_part = (float*)alloc((size_t)KSPLIT * MROWS * NXP * 4);
    float* op_part = (float*)alloc((size_t)OPKS * MROWS * DD * 4);

    // all weight conversions + a2T table in one launch
    {
        int ntot = N1 + N2 + N3 + N4 + N5;
        cvt_all_k<<<(ntot + 255) / 256, 256, 0, stream>>>(
            in_proj_w, x_proj_w, dt_proj_w, out_proj_w, A_log,
            w_in, w_xp, w_dt, w_out, a2T);
    }

    for (int i = 0; i < 4; i++) {
        const float* x_src = (i == 0) ? x_in : x_buf;
        // 1. rmsnorm (layer 0 only; later layers get xn_bf from fused op_reduce_norm)
        if (i == 0)
            rmsnorm_k<<<MROWS, 256, 0, stream>>>(x_src, norm_w, xn_bf);
        // 2. in_proj: (2048 x 3072), bf16 out
        gemm_bt<1><<<dim3(MROWS / 128, 3072 / 128), 256, 0, stream>>>(
            xn_bf, w_in + (size_t)i * 3072 * 768, nullptr, xz_bf,
            MROWS, 2 * DI, DD);
        // 3. causal conv + silu + silu(z) gate (bf16 outputs)
        conv_silu_k<<<(MROWS * (DI / 4) + 255) / 256, 256, 0, stream>>>(
            xz_bf, conv_w + (size_t)i * DI * 4, conv_b + (size_t)i * DI, xc_bf, gz_bf);
        // 4. x_proj split-K + reduce -> xdbl f32 + padded bf16 dt
        gemm_xp<<<dim3(MROWS / 64, KSPLIT), 256, 0, stream>>>(
            xc_bf, w_xp + (size_t)i * NXP * DI, xp_part);
        xp_reduce_k<<<(MROWS * NXP + 255) / 256, 256, 0, stream>>>(xp_part, xdbl, dt_bf);
        // 5. scan v6: one serial pass (yloc/Scum/P/S) -> compose -> parallel corr
        scanA_k<<<dim3(DI / 16, BB, NC / 2), 256, 0, stream>>>(
            dt_bf, w_dt + (size_t)i * DI * DTPAD, dt_proj_b + (size_t)i * DI,
            xc_bf, xdbl, A_log + (size_t)i * DI * DSTATE, Pbuf, Sbuf, ylbuf, scbuf);
        compose_k<<<(BB * DI * DSTATE) / 256, 256, 0, stream>>>(Pbuf, Sbuf, H0T);
        corr_k<<<dim3(24, BB, NC), 256, 0, stream>>>(
            ylbuf, scbuf, xdbl, H0T, a2T + (size_t)i * DSTATE * DI,
            xc_bf, gz_bf, D_skip + (size_t)i * DI, y_bf);
        // 6. out_proj split-K -> partials; fused reduce + residual + next rmsnorm
        gemm_bt<5><<<dim3(MROWS / 128, DD / 128, OPKS), 256, 0, stream>>>(
            y_bf, w_out + (size_t)i * DD * DI, op_part, nullptr,
            MROWS, DD, DI);
        op_reduce_norm_k<<<MROWS, 256, 0, stream>>>(
            op_part, x_src, norm_w + ((i + 1) & 3) * DD, x_buf, xn_bf);
    }

    head_norm_k<<<BB, 256, 0, stream>>>(x_buf, fnw, xnl);
    head_h1_k<<<dim3(BB, DD / 64), 256, 0, stream>>>(xnl, h1w, h1b, hbuf);
    head_out_k<<<BB, 256, 0, stream>>>(hbuf, hnw, h2w, h2b, out);
}

// Round 7
// 626.518 us; speedup vs baseline: 1.0707x; 1.0539x over previous
//
#include <hip/hip_runtime.h>
#include <hip/hip_bf16.h>
#include <math.h>

typedef __bf16 bf16;
typedef __bf16 bf16x4 __attribute__((ext_vector_type(4)));
typedef __bf16 bf16x8 __attribute__((ext_vector_type(8)));
typedef float floatx4 __attribute__((ext_vector_type(4)));

#define BB 2
#define LL 1024
#define DD 768
#define DI 1536
#define MROWS 2048   // B*L
#define NXP 80       // dt_rank + 2*d_state
#define DTRANK 48
#define DTPAD 64     // dt K padded to 64
#define DSTATE 16
#define NC 16        // scan chunks
#define CLEN 64      // scan chunk length (NC*CLEN == LL)
#define KSPLIT 16    // x_proj split-K factor (K-seg = 96)
#define OPKS 4       // out_proj split-K factor (K-seg = 384)
#define LOG2E 1.4426950408889634f
#define LN2   0.6931471805599453f
#define TROW 132     // floats per sdpT/sbcT row (128 data + 4 pad)
#define SYROW 68     // floats per syT/sST row

// async global->LDS, 16 B per lane; lds dest must be wave-uniform base (+lane*16)
__device__ __forceinline__ void ld16(void* lds, const void* g) {
    __builtin_amdgcn_global_load_lds(
        (const __attribute__((address_space(1))) void*)g,
        (__attribute__((address_space(3))) void*)lds, 16, 0, 0);
}

// drain this wave's outstanding async global_load_lds before signalling barrier.
__device__ __forceinline__ void wait_vm0() {
    asm volatile("s_waitcnt vmcnt(0)" ::: "memory");
}

// DPP row-reduce over 16 lanes (one DPP row): lane 0 of each row gets the sum.
__device__ __forceinline__ float row16_sum(float x) {
    float t;
    t = __int_as_float(__builtin_amdgcn_update_dpp(0, __float_as_int(x), 0x111, 0xF, 0xF, true)); x += t;
    t = __int_as_float(__builtin_amdgcn_update_dpp(0, __float_as_int(x), 0x112, 0xF, 0xF, true)); x += t;
    t = __int_as_float(__builtin_amdgcn_update_dpp(0, __float_as_int(x), 0x114, 0xF, 0xF, true)); x += t;
    t = __int_as_float(__builtin_amdgcn_update_dpp(0, __float_as_int(x), 0x118, 0xF, 0xF, true)); x += t;
    return x;
}

// raw v_exp_f32 / v_log_f32 (no ocml denormal fixup)
__device__ __forceinline__ float exp2_raw(float x) {
#if __has_builtin(__builtin_amdgcn_exp2f)
    return __builtin_amdgcn_exp2f(x);
#else
    float r; asm("v_exp_f32 %0, %1" : "=v"(r) : "v"(x)); return r;
#endif
}
__device__ __forceinline__ float log2_raw(float x) {
#if __has_builtin(__builtin_amdgcn_logf)
    return __builtin_amdgcn_logf(x);
#else
    float r; asm("v_log_f32 %0, %1" : "=v"(r) : "v"(x)); return r;
#endif
}
// softplus(v) = ln(1+exp(v)) via raw exp2/log2; guard large v (exp2 overflow).
__device__ __forceinline__ float softplus_fast(float v) {
    float t  = exp2_raw(v * LOG2E);
    float sp = log2_raw(1.f + t) * LN2;
    return (v > 20.f) ? v : sp;
}

// ---------------------------------------------------------------- all weight cvt in one kernel
#define N1 (4 * 3072 * 768)
#define N2 (4 * NXP * DI)
#define N3 (4 * DI * DTPAD)
#define N4 (4 * DD * DI)
#define N5 (4 * DSTATE * DI)   // a2T[layer][n][d] = -exp(A_log[layer,d,n])*log2(e)
__global__ __launch_bounds__(256) void cvt_all_k(const float* __restrict__ in_proj_w,
                                                 const float* __restrict__ x_proj_w,
                                                 const float* __restrict__ dt_proj_w,
                                                 const float* __restrict__ out_proj_w,
                                                 const float* __restrict__ A_log,
                                                 bf16* __restrict__ w_in,
                                                 bf16* __restrict__ w_xp,
                                                 bf16* __restrict__ w_dt,
                                                 bf16* __restrict__ w_out,
                                                 float* __restrict__ a2T) {
    int i = blockIdx.x * 256 + threadIdx.x;
    if (i < N1) { w_in[i] = (bf16)in_proj_w[i]; return; }
    i -= N1;
    if (i < N2) { w_xp[i] = (bf16)x_proj_w[i]; return; }
    i -= N2;
    if (i < N3) {
        int row = i >> 6, c = i & 63;
        w_dt[i] = (c < DTRANK) ? (bf16)dt_proj_w[row * DTRANK + c] : (bf16)0.f;
        return;
    }
    i -= N3;
    if (i < N4) { w_out[i] = (bf16)out_proj_w[i]; return; }
    i -= N4;
    if (i < N5) {
        int layer = i / (DSTATE * DI);
        int rem   = i - layer * (DSTATE * DI);
        int n     = rem / DI;
        int d     = rem - n * DI;
        a2T[i] = -__expf(A_log[(size_t)layer * DI * DSTATE + d * DSTATE + n]) * LOG2E;
    }
}

// ---------------------------------------------------------------- rmsnorm -> bf16 (layer 0 only)
__global__ __launch_bounds__(256) void rmsnorm_k(const float* __restrict__ x,
                                                 const float* __restrict__ w,
                                                 bf16* __restrict__ out) {
    int row = blockIdx.x;
    const float* xr = x + (size_t)row * DD;
    int tid = threadIdx.x;
    float v[3]; float ss = 0.f;
    for (int j = 0; j < 3; j++) { v[j] = xr[tid + j * 256]; ss += v[j] * v[j]; }
    for (int o = 1; o < 64; o <<= 1) ss += __shfl_xor(ss, o, 64);
    __shared__ float sred[4];
    if ((tid & 63) == 0) sred[tid >> 6] = ss;
    __syncthreads();
    float scale = rsqrtf((sred[0] + sred[1] + sred[2] + sred[3]) / (float)DD + 1e-6f);
    for (int j = 0; j < 3; j++) {
        int c = tid + j * 256;
        out[(size_t)row * DD + c] = (bf16)(v[j] * scale * w[c]);
    }
}

// ---------------------------------------------------------------- GEMM: C = A @ W^T
// MODE 1: store bf16 | MODE 5: split-K partials f32
template <int MODE>
__global__ __launch_bounds__(256) void gemm_bt(const bf16* __restrict__ A,
                                               const bf16* __restrict__ W,
                                               float* __restrict__ Cf,
                                               bf16* __restrict__ Cb,
                                               int M, int N, int K) {
    __shared__ bf16 As[128][32];
    __shared__ bf16 Ws[128][32];
    const int tid  = threadIdx.x;
    const int m0   = blockIdx.x * 128;
    const int n0   = blockIdx.y * 128;
    const int wave = tid >> 6;
    const int lane = tid & 63;
    const int wm   = (wave >> 1) * 64;
    const int wn   = (wave & 1) * 64;
    const int lrow = lane & 15;
    const int quad = lane >> 4;

    int kbeg = 0, kend = K;
    if constexpr (MODE == 5) {
        int kseg = K / gridDim.z;
        kbeg = blockIdx.z * kseg;
        kend = kbeg + kseg;
        Cf  += (size_t)blockIdx.z * M * N;
    }

    floatx4 acc[4][4];
    for (int mi = 0; mi < 4; mi++)
        for (int ni = 0; ni < 4; ni++) acc[mi][ni] = (floatx4){0.f, 0.f, 0.f, 0.f};

    const int r0  = tid >> 2;        // 0..63
    const int r1  = r0 + 64;         // 64..127
    const int seg = (tid & 3) * 8;   // 0,8,16,24
    char* asb0 = (char*)As + wave * 1024;
    char* asb1 = (char*)As + 4096 + wave * 1024;
    char* wsb0 = (char*)Ws + wave * 1024;
    char* wsb1 = (char*)Ws + 4096 + wave * 1024;

    for (int kb = kbeg; kb < kend; kb += 32) {
        int gk = kb + seg;
        __syncthreads();   // previous iteration's LDS reads done
        ld16(asb0, A + (size_t)(m0 + r0) * K + gk);
        ld16(asb1, A + (size_t)(m0 + r1) * K + gk);
        ld16(wsb0, W + (size_t)(n0 + r0) * K + gk);
        ld16(wsb1, W + (size_t)(n0 + r1) * K + gk);
        wait_vm0();        // this wave's async LDS fills landed
        __syncthreads();   // all waves' fills landed -> tiles ready
        bf16x8 af[4], wf[4];
        for (int mi = 0; mi < 4; mi++) af[mi] = *(const bf16x8*)&As[wm + mi * 16 + lrow][quad * 8];
        for (int ni = 0; ni < 4; ni++) wf[ni] = *(const bf16x8*)&Ws[wn + ni * 16 + lrow][quad * 8];
        for (int mi = 0; mi < 4; mi++)
            for (int ni = 0; ni < 4; ni++)
                acc[mi][ni] = __builtin_amdgcn_mfma_f32_16x16x32_bf16(af[mi], wf[ni], acc[mi][ni], 0, 0, 0);
    }
    for (int mi = 0; mi < 4; mi++) {
        int rowb = m0 + wm + mi * 16 + quad * 4;
        for (int ni = 0; ni < 4; ni++) {
            int col = n0 + wn + ni * 16 + lrow;
            for (int r = 0; r < 4; r++) {
                int row = rowb + r;
                float v = acc[mi][ni][r];
                if constexpr (MODE == 1) Cb[(size_t)row * N + col] = (bf16)v;
                else                     Cf[(size_t)row * N + col] = v;
            }
        }
    }
}

// ---------------------------------------------------------------- out_proj partials + residual + NEXT layer rmsnorm (fused)
__global__ __launch_bounds__(256) void op_reduce_norm_k(const float* __restrict__ part,
                                                        const float* __restrict__ resid,
                                                        const float* __restrict__ nw,
                                                        float* __restrict__ xout,
                                                        bf16* __restrict__ xnb) {
    int row = blockIdx.x;
    int tid = threadIdx.x;
    float v[3]; float ss = 0.f;
    for (int j = 0; j < 3; j++) {
        int c = tid + j * 256;
        size_t idx = (size_t)row * DD + c;
        float s = resid[idx];
        for (int ks = 0; ks < OPKS; ks++) s += part[(size_t)ks * MROWS * DD + idx];
        v[j] = s;
        xout[idx] = s;
        ss += s * s;
    }
    for (int o = 1; o < 64; o <<= 1) ss += __shfl_xor(ss, o, 64);
    __shared__ float sred[4];
    if ((tid & 63) == 0) sred[tid >> 6] = ss;
    __syncthreads();
    float scale = rsqrtf((sred[0] + sred[1] + sred[2] + sred[3]) / (float)DD + 1e-6f);
    for (int j = 0; j < 3; j++) {
        int c = tid + j * 256;
        xnb[(size_t)row * DD + c] = (bf16)(v[j] * scale * nw[c]);
    }
}

// ---------------------------------------------------------------- x_proj split-K GEMM
__global__ __launch_bounds__(256) void gemm_xp(const bf16* __restrict__ A,
                                               const bf16* __restrict__ W,
                                               float* __restrict__ part) {
    __shared__ bf16 As[64][40];
    __shared__ bf16 Ws[128][40];
    const int tid  = threadIdx.x;
    const int m0   = blockIdx.x * 64;
    const int ks   = blockIdx.y;
    const int k0   = ks * (DI / KSPLIT);
    const int wave = tid >> 6;
    const int lane = tid & 63;
    const int lrow = lane & 15;
    const int quad = lane >> 4;
    const int wm   = wave * 16;

    floatx4 acc[5];
    for (int ni = 0; ni < 5; ni++) acc[ni] = (floatx4){0.f, 0.f, 0.f, 0.f};

    const int ra  = tid >> 2;
    const int rw1 = ra + 64;
    const int seg = (tid & 3) * 8;

    for (int kb = 0; kb < DI / KSPLIT; kb += 32) {
        int gk = k0 + kb + seg;
        bf16x8 va = *(const bf16x8*)(A + (size_t)(m0 + ra) * DI + gk);
        bf16x8 vw0, vw1;
        if (ra < NXP) vw0 = *(const bf16x8*)(W + (size_t)ra * DI + gk);
        else          for (int j = 0; j < 8; j++) vw0[j] = (bf16)0.f;
        if (rw1 < NXP) vw1 = *(const bf16x8*)(W + (size_t)rw1 * DI + gk);
        else           for (int j = 0; j < 8; j++) vw1[j] = (bf16)0.f;
        __syncthreads();
        *(bf16x8*)&As[ra][seg]  = va;
        *(bf16x8*)&Ws[ra][seg]  = vw0;
        *(bf16x8*)&Ws[rw1][seg] = vw1;
        __syncthreads();
        bf16x8 af = *(const bf16x8*)&As[wm + lrow][quad * 8];
        for (int ni = 0; ni < 5; ni++) {
            bf16x8 wf = *(const bf16x8*)&Ws[ni * 16 + lrow][quad * 8];
            acc[ni] = __builtin_amdgcn_mfma_f32_16x16x32_bf16(af, wf, acc[ni], 0, 0, 0);
        }
    }
    float* pout = part + (size_t)ks * MROWS * NXP;
    for (int ni = 0; ni < 5; ni++) {
        int col = ni * 16 + lrow;
        for (int r = 0; r < 4; r++) {
            int row = m0 + wm + quad * 4 + r;
            pout[(size_t)row * NXP + col] = acc[ni][r];
        }
    }
}

// reduce split-K partials -> xdbl f32 + padded bf16 dt
__global__ __launch_bounds__(256) void xp_reduce_k(const float* __restrict__ part,
                                                   float* __restrict__ xdbl,
                                                   bf16* __restrict__ dtbf) {
    int idx = blockIdx.x * 256 + threadIdx.x;
    if (idx >= MROWS * NXP) return;
    float s = 0.f;
    for (int j = 0; j < KSPLIT; j++) s += part[(size_t)j * MROWS * NXP + idx];
    xdbl[idx] = s;
    int m = idx / NXP, c = idx - m * NXP;
    if (c < DTRANK)      dtbf[m * DTPAD + c] = (bf16)s;
    else if (c < DTPAD)  dtbf[m * DTPAD + c] = (bf16)0.f;
}

// ---------------------------------------------------------------- causal depthwise conv + silu + gate (4-wide, bf16 outputs)
__global__ __launch_bounds__(256) void conv_silu_k(const bf16* __restrict__ xz,
                                                   const float* __restrict__ cw,
                                                   const float* __restrict__ cb,
                                                   bf16* __restrict__ xcb,
                                                   bf16* __restrict__ gzb) {
    int t = blockIdx.x * 256 + threadIdx.x;
    if (t >= MROWS * (DI / 4)) return;
    int m = t / (DI / 4);
    int d = (t - m * (DI / 4)) * 4;
    int l = m & (LL - 1);
    float acc[4];
    floatx4 cwv[4];
    for (int q = 0; q < 4; q++) {
        acc[q] = cb[d + q];
        cwv[q] = *(const floatx4*)&cw[(d + q) * 4];
    }
    for (int k = 0; k < 4; k++) {
        int lp = l - 3 + k;
        if (lp >= 0) {
            bf16x4 v = *(const bf16x4*)&xz[(size_t)(m - 3 + k) * (2 * DI) + d];
            for (int q = 0; q < 4; q++) acc[q] += (float)v[q] * cwv[q][k];
        }
    }
    bf16x4 xo, go;
    bf16x4 z4 = *(const bf16x4*)&xz[(size_t)m * (2 * DI) + DI + d];
    for (int q = 0; q < 4; q++) {
        float s = acc[q] / (1.f + __expf(-acc[q]));
        xo[q] = (bf16)s;
        float zv = (float)z4[q];
        go[q] = (bf16)(zv / (1.f + __expf(-zv)));
    }
    *(bf16x4*)&xcb[(size_t)m * DI + d] = xo;
    *(bf16x4*)&gzb[(size_t)m * DI + d] = go;
}

// ---------------------------------------------------------------- selective scan v7: single serial pass + parallel correction
// v6 post-mortem: 2-chunks/block halved block count (1536) -> queued occupancy
// collapsed (VALUBusy 40%). R0/v4 evidence: 3072 one-chunk blocks reach
// 53-85% VALUBusy. v7: one chunk per block (grid z=NC), reg-staged operands,
// interleaved (yloc,Scum) float2 emit (coalesced 8B stores), fast softplus.
__global__ __launch_bounds__(256) void scanA_k(const bf16* __restrict__ dtb,
                                               const bf16* __restrict__ wdt,
                                               const float* __restrict__ dtbias,
                                               const bf16* __restrict__ xcb,
                                               const float* __restrict__ xdbl,
                                               const float* __restrict__ A_log,
                                               float* __restrict__ Pbuf,
                                               float* __restrict__ Sbuf,
                                               float2* __restrict__ ylsc) {
    const int b   = blockIdx.y;
    const int d0  = blockIdx.x * 16;
    const int c   = blockIdx.z;
    const int tid = threadIdx.x;
    const int dl  = tid >> 4;
    const int n   = tid & 15;
    const int wv  = tid >> 6;
    const int lane = tid & 63;
    const int lr  = lane & 15;
    const int q   = lane >> 4;
    const int l0  = c * CLEN;

    const float a2 = -__expf(A_log[(size_t)(d0 + dl) * DSTATE + n]) * LOG2E;
    const float bi = dtbias[d0 + lr];

    __shared__ __align__(16) bf16  sxc[CLEN][16];   // conv out (DMA)
    __shared__ __align__(16) float sdpT[16][TROW];  // [d][2i]=(dv), [2i+1]=(dv*xc)
    __shared__ __align__(16) float sbcT[16][TROW];  // [n][2i]=(B), [2i+1]=(C)
    __shared__ __align__(16) float syT[16][SYROW];  // [d][i] yloc
    __shared__ __align__(16) float sST[16][SYROW];  // [d][i] Scum

    // persistent w_dt fragments (regs, L2-resident)
    const bf16x8 wf0 = *(const bf16x8*)&wdt[(size_t)(d0 + lr) * DTPAD + q * 8];
    const bf16x8 wf1 = *(const bf16x8*)&wdt[(size_t)(d0 + lr) * DTPAD + 32 + q * 8];

    // ---- stage: A-frags + B/C to regs, xc via DMA ----
    bf16x8 a0, a1;
    {
        const bf16* r = &dtb[(size_t)(b * LL + l0 + 16 * wv + lr) * DTPAD + q * 8];
        a0 = *(const bf16x8*)r;
        a1 = *(const bf16x8*)(r + 32);
    }
    float Bv[4], Cv[4];
    #pragma unroll
    for (int k2 = 0; k2 < 4; ++k2) {
        int ii = (tid + 256 * k2) >> 4;
        const float* p = &xdbl[(size_t)(b * LL + l0 + ii) * NXP + DTRANK + n];
        Bv[k2] = p[0];
        Cv[k2] = p[DSTATE];
    }
    if (tid < 128) {
        int r2 = tid >> 1, c2 = tid & 1;
        ld16((char*)&sxc[0][0] + (tid & ~63) * 16,
             xcb + (size_t)(b * LL + l0 + r2) * DI + d0 + c2 * 8);
    }
    wait_vm0();
    __syncthreads();

    // ---- delta tile via MFMA + fast softplus; pack transposed operands ----
    {
        floatx4 dacc = (floatx4){0.f, 0.f, 0.f, 0.f};
        dacc = __builtin_amdgcn_mfma_f32_16x16x32_bf16(a0, wf0, dacc, 0, 0, 0);
        dacc = __builtin_amdgcn_mfma_f32_16x16x32_bf16(a1, wf1, dacc, 0, 0, 0);
        float vv[4], xvv[4];
        #pragma unroll
        for (int r = 0; r < 4; ++r) {
            int l = 16 * wv + q * 4 + r;
            vv[r]  = softplus_fast(dacc[r] + bi);
            xvv[r] = (float)sxc[l][lr];
        }
        int L0 = 16 * wv + q * 4;
        *(float4*)&sdpT[lr][2 * L0] =
            make_float4(vv[0], vv[0] * xvv[0], vv[1], vv[1] * xvv[1]);
        *(float4*)&sdpT[lr][2 * L0 + 4] =
            make_float4(vv[2], vv[2] * xvv[2], vv[3], vv[3] * xvv[3]);
        #pragma unroll
        for (int k2 = 0; k2 < 4; ++k2) {
            int ii = (tid + 256 * k2) >> 4;
            *(float2*)&sbcT[n][2 * ii] = make_float2(Bv[k2], Cv[k2]);
        }
    }
    __syncthreads();

    // ---- 64-step local scan: 8 groups of 8, register double-buffered prefetch ----
    {
        float h = 0.f, sdc = 0.f;
        const float4* dpr = (const float4*)&sdpT[dl][0];
        const float4* bcr = (const float4*)&sbcT[n][0];
        float4 dA[4], bA[4], dB2[4], bB2[4];
        float y4[4], s4[4];
        #pragma unroll
        for (int t = 0; t < 4; ++t) { dA[t] = dpr[t]; bA[t] = bcr[t]; }
        #pragma unroll
        for (int g = 0; g < 8; ++g) {
            #pragma unroll
            for (int t = 0; t < 4; ++t) {
                if (g + 1 < 8) {
                    if ((g & 1) == 0) { dB2[t] = dpr[(g + 1) * 4 + t]; bB2[t] = bcr[(g + 1) * 4 + t]; }
                    else              { dA[t]  = dpr[(g + 1) * 4 + t]; bA[t]  = bcr[(g + 1) * 4 + t]; }
                }
            }
            #pragma unroll
            for (int i = 0; i < 8; ++i) {
                float4 v = ((g & 1) == 0) ? dA[i >> 1] : dB2[i >> 1];
                float4 w = ((g & 1) == 0) ? bA[i >> 1] : bB2[i >> 1];
                float dvx = (i & 1) ? v.z : v.x;
                float dpy = (i & 1) ? v.w : v.y;
                float bx  = (i & 1) ? w.z : w.x;
                float cy  = (i & 1) ? w.w : w.y;
                float e = exp2_raw(dvx * a2);
                h = __builtin_fmaf(e, h, dpy * bx);
                sdc += dvx;
                y4[i & 3] = row16_sum(h * cy);
                s4[i & 3] = sdc;
                if ((i & 3) == 3 && n == 0) {
                    *(floatx4*)&syT[dl][g * 8 + i - 3] =
                        (floatx4){y4[0], y4[1], y4[2], y4[3]};
                    *(floatx4*)&sST[dl][g * 8 + i - 3] =
                        (floatx4){s4[0], s4[1], s4[2], s4[3]};
                }
            }
        }
        size_t o = (((size_t)c * BB + b) * DI + (d0 + dl)) * DSTATE + n;
        Pbuf[o] = exp2_raw(a2 * sdc);
        Sbuf[o] = h;
    }
    __syncthreads();

    // ---- emit (yloc, Scum) interleaved float2, coalesced 8B stores ----
    #pragma unroll
    for (int k2 = 0; k2 < 4; ++k2) {
        int idx = tid + 256 * k2, ii = idx >> 4, dd = idx & 15;
        ylsc[(size_t)(b * LL + l0 + ii) * DI + d0 + dd] =
            make_float2(syT[dd][ii], sST[dd][ii]);
    }
}

// Prefix-compose (P,S) over chunks -> H0T[c][n][d] = h entering chunk c (transposed).
__global__ __launch_bounds__(256) void compose_k(const float* __restrict__ P,
                                                 const float* __restrict__ S,
                                                 float* __restrict__ H0T) {
    int idx = blockIdx.x * 256 + threadIdx.x;   // over BB*DI*DSTATE, (b,d,n) order
    const size_t stride = (size_t)BB * DI * DSTATE;
    int b = idx / (DI * DSTATE);
    int rest = idx - b * (DI * DSTATE);
    int d = rest >> 4;
    int n = rest & 15;
    float h = 0.f;
    #pragma unroll
    for (int c = 0; c < NC; ++c) {
        H0T[((size_t)c * BB + b) * (DSTATE * DI) + (size_t)n * DI + d] = h;
        h = __builtin_fmaf(P[(size_t)c * stride + idx], h, S[(size_t)c * stride + idx]);
    }
}

// Parallel correction: y = (yloc + sum_n C*exp2(a2*Scum)*h0 + xc*D) * gz.
// grid (24, BB, NC); thread handles 4 l's (stride 16 in chunk) x 4 consecutive d.
__global__ __launch_bounds__(256) void corr_k(const float2* __restrict__ ylsc,
                                              const float* __restrict__ xdbl,
                                              const float* __restrict__ H0T,
                                              const float* __restrict__ a2T,
                                              const bf16* __restrict__ xcb,
                                              const bf16* __restrict__ gzb,
                                              const float* __restrict__ Dskip,
                                              bf16* __restrict__ ybf) {
    const int b = blockIdx.y, c = blockIdx.z;
    const int tid = threadIdx.x;
    const int t6 = blockIdx.x * 256 + tid;        // 0..6143
    const int dq   = (t6 % 384) * 4;              // d quad
    const int loff = t6 / 384;                    // 0..15

    __shared__ __align__(16) float sC[CLEN][16];  // C tile (d-independent)
    {
        int l = tid >> 2, nn = (tid & 3) * 4;
        *(float4*)&sC[l][nn] =
            *(const float4*)&xdbl[(size_t)(b * LL + c * CLEN + l) * NXP + DTRANK + DSTATE + nn];
    }
    __syncthreads();

    const float* h0base = H0T + ((size_t)c * BB + b) * (DSTATE * DI);
    int m0_ = b * LL + c * CLEN + loff;
    floatx4 acc[4];
    float4 sc[4];
    #pragma unroll
    for (int s = 0; s < 4; ++s) {
        size_t mo = (size_t)(m0_ + s * 16) * DI + dq;
        float4 u0 = *(const float4*)&ylsc[mo];       // (yl0,sc0,yl1,sc1)
        float4 u1 = *(const float4*)&ylsc[mo + 2];   // (yl2,sc2,yl3,sc3)
        acc[s] = (floatx4){u0.x, u0.z, u1.x, u1.z};
        sc[s]  = make_float4(u0.y, u0.w, u1.y, u1.w);
    }
    #pragma unroll
    for (int n = 0; n < DSTATE; ++n) {
        float4 a2v = *(const float4*)&a2T[(size_t)n * DI + dq];
        float4 h0v = *(const float4*)&h0base[(size_t)n * DI + dq];
        #pragma unroll
        for (int s = 0; s < 4; ++s) {
            float Cn = sC[loff + s * 16][n];
            acc[s][0] = __builtin_fmaf(Cn * h0v.x, exp2_raw(a2v.x * sc[s].x), acc[s][0]);
            acc[s][1] = __builtin_fmaf(Cn * h0v.y, exp2_raw(a2v.y * sc[s].y), acc[s][1]);
            acc[s][2] = __builtin_fmaf(Cn * h0v.z, exp2_raw(a2v.z * sc[s].z), acc[s][2]);
            acc[s][3] = __builtin_fmaf(Cn * h0v.w, exp2_raw(a2v.w * sc[s].w), acc[s][3]);
        }
    }
    float4 Dsk = *(const float4*)&Dskip[dq];
    #pragma unroll
    for (int s = 0; s < 4; ++s) {
        size_t mo = (size_t)(m0_ + s * 16) * DI + dq;
        bf16x4 xc4 = *(const bf16x4*)&xcb[mo];
        bf16x4 gz4 = *(const bf16x4*)&gzb[mo];
        bf16x4 yo;
        yo[0] = (bf16)((acc[s][0] + (float)xc4[0] * Dsk.x) * (float)gz4[0]);
        yo[1] = (bf16)((acc[s][1] + (float)xc4[1] * Dsk.y) * (float)gz4[1]);
        yo[2] = (bf16)((acc[s][2] + (float)xc4[2] * Dsk.z) * (float)gz4[2]);
        yo[3] = (bf16)((acc[s][3] + (float)xc4[3] * Dsk.w) * (float)gz4[3]);
        *(bf16x4*)&ybf[mo] = yo;
    }
}

// ---------------------------------------------------------------- head
__global__ __launch_bounds__(256) void head_norm_k(const float* __restrict__ x,
                                                   const float* __restrict__ fnw,
                                                   float* __restrict__ xn_buf) {
    int b = blockIdx.x;
    int tid = threadIdx.x;
    const float* xr = x + ((size_t)b * LL + (LL - 1)) * DD;
    __shared__ float sred[4];
    float v[3]; float ss = 0.f;
    for (int j = 0; j < 3; j++) { v[j] = xr[tid + j * 256]; ss += v[j] * v[j]; }
    for (int o = 1; o < 64; o <<= 1) ss += __shfl_xor(ss, o, 64);
    if ((tid & 63) == 0) sred[tid >> 6] = ss;
    __syncthreads();
    float scale = rsqrtf((sred[0] + sred[1] + sred[2] + sred[3]) / (float)DD + 1e-6f);
    for (int j = 0; j < 3; j++) {
        int c = tid + j * 256;
        xn_buf[(size_t)b * DD + c] = v[j] * scale * fnw[c];
    }
}

__global__ __launch_bounds__(256) void head_h1_k(const float* __restrict__ xn_buf,
                                                 const float* __restrict__ h1w,
                                                 const float* __restrict__ h1b,
                                                 float* __restrict__ h_buf) {
    int b  = blockIdx.x;
    int o0 = blockIdx.y * 64;
    int tid = threadIdx.x;
    __shared__ float sx[DD];
    for (int c = tid; c < DD; c += 256) sx[c] = xn_buf[(size_t)b * DD + c];
    __syncthreads();
    int wave = tid >> 6, lane = tid & 63;
    for (int j = 0; j < 16; j++) {
        int o = o0 + wave * 16 + j;
        const float* wrow = h1w + (size_t)o * DD;
        float acc = 0.f;
        for (int k = 0; k < 12; k++) {
            int c = lane + 64 * k;
            acc += wrow[c] * sx[c];
        }
        for (int off = 1; off < 64; off <<= 1) acc += __shfl_xor(acc, off, 64);
        if (lane == 0) h_buf[(size_t)b * DD + o] = acc + h1b[o];
    }
}

__global__ __launch_bounds__(256) void head_out_k(const float* __restrict__ h_buf,
                                                  const float* __restrict__ hnw,
                                                  const float* __restrict__ h2w,
                                                  const float* __restrict__ h2b,
                                                  float* __restrict__ out) {
    int b = blockIdx.x;
    int tid = threadIdx.x;
    __shared__ float hh[DD];
    __shared__ float sred[4];
    const float* hr = h_buf + (size_t)b * DD;
    float ss = 0.f;
    for (int c = tid; c < DD; c += 256) { float v = hr[c]; ss += v * v; }
    for (int o = 1; o < 64; o <<= 1) ss += __shfl_xor(ss, o, 64);
    if ((tid & 63) == 0) sred[tid >> 6] = ss;
    __syncthreads();
    float sc = rsqrtf((sred[0] + sred[1] + sred[2] + sred[3]) / (float)DD + 1e-6f);
    for (int c = tid; c < DD; c += 256) {
        float v = hr[c] * sc * hnw[c];
        hh[c] = 0.5f * v * (1.f + erff(v * 0.70710678118f));
    }
    __syncthreads();
    int w = tid >> 6, lane = tid & 63;
    for (int j = w; j < 10; j += 4) {
        float acc = 0.f;
        const float* wrow = h2w + (size_t)j * DD;
        for (int c = lane; c < DD; c += 64) acc += hh[c] * wrow[c];
        for (int o = 1; o < 64; o <<= 1) acc += __shfl_xor(acc, o, 64);
        if (lane == 0) out[b * 10 + j] = acc + h2b[j];
    }
}

// ----------------------------------------------------------------
extern "C" void kernel_launch(void* const* d_in, const int* in_sizes, int n_in,
                              void* d_out, int out_size, void* d_ws, size_t ws_size,
                              hipStream_t stream) {
    const float* x_in      = (const float*)d_in[0];
    const float* norm_w    = (const float*)d_in[1];
    const float* in_proj_w = (const float*)d_in[2];
    const float* conv_w    = (const float*)d_in[3];
    const float* conv_b    = (const float*)d_in[4];
    const float* x_proj_w  = (const float*)d_in[5];
    const float* dt_proj_w = (const float*)d_in[6];
    const float* dt_proj_b = (const float*)d_in[7];
    const float* A_log     = (const float*)d_in[8];
    const float* D_skip    = (const float*)d_in[9];
    const float* out_proj_w= (const float*)d_in[10];
    const float* fnw       = (const float*)d_in[11];
    const float* h1w       = (const float*)d_in[12];
    const float* h1b       = (const float*)d_in[13];
    const float* hnw       = (const float*)d_in[14];
    const float* h2w       = (const float*)d_in[15];
    const float* h2b       = (const float*)d_in[16];
    float* out = (float*)d_out;

    char* ws = (char*)d_ws;
    size_t off = 0;
    auto alloc = [&](size_t bytes) -> void* {
        void* p = ws + off;
        off += (bytes + 255) & ~(size_t)255;
        return p;
    };
    bf16* w_in  = (bf16*)alloc((size_t)N1 * 2);
    bf16* w_xp  = (bf16*)alloc((size_t)N2 * 2);
    bf16* w_dt  = (bf16*)alloc((size_t)N3 * 2);
    bf16* w_out = (bf16*)alloc((size_t)N4 * 2);
    float* a2T  = (float*)alloc((size_t)N5 * 4);
    bf16* xn_bf = (bf16*)alloc((size_t)MROWS * DD * 2);
    bf16* xz_bf = (bf16*)alloc((size_t)MROWS * 2 * DI * 2);
    bf16* xc_bf = (bf16*)alloc((size_t)MROWS * DI * 2);
    bf16* gz_bf = (bf16*)alloc((size_t)MROWS * DI * 2);
    float* xdbl = (float*)alloc((size_t)MROWS * NXP * 4);
    bf16* dt_bf = (bf16*)alloc((size_t)MROWS * DTPAD * 2);
    bf16* y_bf  = (bf16*)alloc((size_t)MROWS * DI * 2);
    float* x_buf= (float*)alloc((size_t)MROWS * DD * 4);
    float* Pbuf = (float*)alloc((size_t)NC * BB * DI * DSTATE * 4);
    float* Sbuf = (float*)alloc((size_t)NC * BB * DI * DSTATE * 4);
    float* H0T  = (float*)alloc((size_t)NC * BB * DI * DSTATE * 4);
    float2* ylsc= (float2*)alloc((size_t)MROWS * DI * 8);
    float* xnl  = (float*)alloc((size_t)BB * DD * 4);
    float* hbuf = (float*)alloc((size_t)BB * DD * 4);
    float* xp_part = (float*)alloc((size_t)KSPLIT * MROWS * NXP * 4);
    float* op_part = (float*)alloc((size_t)OPKS * MROWS * DD * 4);

    // all weight conversions + a2T table in one launch
    {
        int ntot = N1 + N2 + N3 + N4 + N5;
        cvt_all_k<<<(ntot + 255) / 256, 256, 0, stream>>>(
            in_proj_w, x_proj_w, dt_proj_w, out_proj_w, A_log,
            w_in, w_xp, w_dt, w_out, a2T);
    }

    for (int i = 0; i < 4; i++) {
        const float* x_src = (i == 0) ? x_in : x_buf;
        // 1. rmsnorm (layer 0 only; later layers get xn_bf from fused op_reduce_norm)
        if (i == 0)
            rmsnorm_k<<<MROWS, 256, 0, stream>>>(x_src, norm_w, xn_bf);
        // 2. in_proj: (2048 x 3072), bf16 out
        gemm_bt<1><<<dim3(MROWS / 128, 3072 / 128), 256, 0, stream>>>(
            xn_bf, w_in + (size_t)i * 3072 * 768, nullptr, xz_bf,
            MROWS, 2 * DI, DD);
        // 3. causal conv + silu + silu(z) gate (bf16 outputs)
        conv_silu_k<<<(MROWS * (DI / 4) + 255) / 256, 256, 0, stream>>>(
            xz_bf, conv_w + (size_t)i * DI * 4, conv_b + (size_t)i * DI, xc_bf, gz_bf);
        // 4. x_proj split-K + reduce -> xdbl f32 + padded bf16 dt
        gemm_xp<<<dim3(MROWS / 64, KSPLIT), 256, 0, stream>>>(
            xc_bf, w_xp + (size_t)i * NXP * DI, xp_part);
        xp_reduce_k<<<(MROWS * NXP + 255) / 256, 256, 0, stream>>>(xp_part, xdbl, dt_bf);
        // 5. scan v7: one serial pass/chunk (3072 blocks) -> compose -> parallel corr
        scanA_k<<<dim3(DI / 16, BB, NC), 256, 0, stream>>>(
            dt_bf, w_dt + (size_t)i * DI * DTPAD, dt_proj_b + (size_t)i * DI,
            xc_bf, xdbl, A_log + (size_t)i * DI * DSTATE, Pbuf, Sbuf, ylsc);
        compose_k<<<(BB * DI * DSTATE) / 256, 256, 0, stream>>>(Pbuf, Sbuf, H0T);
        corr_k<<<dim3(24, BB, NC), 256, 0, stream>>>(
            ylsc, xdbl, H0T, a2T + (size_t)i * DSTATE * DI,
            xc_bf, gz_bf, D_skip + (size_t)i * DI, y_bf);
        // 6. out_proj split-K -> partials; fused reduce + residual + next rmsnorm
        gemm_bt<5><<<dim3(MROWS / 128, DD / 128, OPKS), 256, 0, stream>>>(
            y_bf, w_out + (size_t)i * DD * DI, op_part, nullptr,
            MROWS, DD, DI);
        op_reduce_norm_k<<<MROWS, 256, 0, stream>>>(
            op_part, x_src, norm_w + ((i + 1) & 3) * DD, x_buf, xn_bf);
    }

    head_norm_k<<<BB, 256, 0, stream>>>(x_buf, fnw, xnl);
    head_h1_k<<<dim3(BB, DD / 64), 256, 0, stream>>>(xnl, h1w, h1b, hbuf);
    head_out_k<<<BB, 256, 0, stream>>>(hbuf, hnw, h2w, h2b, out);
}

// Round 8
// 595.110 us; speedup vs baseline: 1.1272x; 1.0528x over previous
//
#include <hip/hip_runtime.h>
#include <hip/hip_bf16.h>
#include <math.h>

typedef __bf16 bf16;
typedef __bf16 bf16x4 __attribute__((ext_vector_type(4)));
typedef __bf16 bf16x8 __attribute__((ext_vector_type(8)));
typedef float floatx4 __attribute__((ext_vector_type(4)));

#define BB 2
#define LL 1024
#define DD 768
#define DI 1536
#define MROWS 2048   // B*L
#define NXP 80       // dt_rank + 2*d_state
#define DTRANK 48
#define DTPAD 64     // dt K padded to 64
#define DSTATE 16
#define NC 16        // scan chunks
#define CLEN 64      // scan chunk length (NC*CLEN == LL)
#define DBLK 64      // scan d-columns per block (v8)
#define KSPLIT 16    // x_proj split-K factor (K-seg = 96)
#define OPKS 4       // out_proj split-K factor (K-seg = 384)
#define LOG2E 1.4426950408889634f
#define LN2   0.6931471805599453f

// async global->LDS, 16 B per lane; lds dest must be wave-uniform base (+lane*16)
__device__ __forceinline__ void ld16(void* lds, const void* g) {
    __builtin_amdgcn_global_load_lds(
        (const __attribute__((address_space(1))) void*)g,
        (__attribute__((address_space(3))) void*)lds, 16, 0, 0);
}

// drain this wave's outstanding async global_load_lds before signalling barrier.
__device__ __forceinline__ void wait_vm0() {
    asm volatile("s_waitcnt vmcnt(0)" ::: "memory");
}

// 4-lane quad sum via DPP quad_perm (lanes grouped by lane[1:0]): all 4 get the sum.
__device__ __forceinline__ float quad4_sum(float x) {
    float t;
    t = __int_as_float(__builtin_amdgcn_update_dpp(0, __float_as_int(x), 0xB1, 0xF, 0xF, true)); x += t; // xor1
    t = __int_as_float(__builtin_amdgcn_update_dpp(0, __float_as_int(x), 0x4E, 0xF, 0xF, true)); x += t; // xor2
    return x;
}

// raw v_exp_f32 / v_log_f32 (no ocml denormal fixup)
__device__ __forceinline__ float exp2_raw(float x) {
#if __has_builtin(__builtin_amdgcn_exp2f)
    return __builtin_amdgcn_exp2f(x);
#else
    float r; asm("v_exp_f32 %0, %1" : "=v"(r) : "v"(x)); return r;
#endif
}
__device__ __forceinline__ float log2_raw(float x) {
#if __has_builtin(__builtin_amdgcn_logf)
    return __builtin_amdgcn_logf(x);
#else
    float r; asm("v_log_f32 %0, %1" : "=v"(r) : "v"(x)); return r;
#endif
}
// softplus(v) = ln(1+exp(v)) via raw exp2/log2; guard large v (exp2 overflow).
__device__ __forceinline__ float softplus_fast(float v) {
    float t  = exp2_raw(v * LOG2E);
    float sp = log2_raw(1.f + t) * LN2;
    return (v > 20.f) ? v : sp;
}

// ---------------------------------------------------------------- all weight cvt in one kernel
#define N1 (4 * 3072 * 768)
#define N2 (4 * NXP * DI)
#define N3 (4 * DI * DTPAD)
#define N4 (4 * DD * DI)
#define N5 (4 * DSTATE * DI)   // a2T[layer][n][d] = -exp(A_log[layer,d,n])*log2(e)
__global__ __launch_bounds__(256) void cvt_all_k(const float* __restrict__ in_proj_w,
                                                 const float* __restrict__ x_proj_w,
                                                 const float* __restrict__ dt_proj_w,
                                                 const float* __restrict__ out_proj_w,
                                                 const float* __restrict__ A_log,
                                                 bf16* __restrict__ w_in,
                                                 bf16* __restrict__ w_xp,
                                                 bf16* __restrict__ w_dt,
                                                 bf16* __restrict__ w_out,
                                                 float* __restrict__ a2T) {
    int i = blockIdx.x * 256 + threadIdx.x;
    if (i < N1) { w_in[i] = (bf16)in_proj_w[i]; return; }
    i -= N1;
    if (i < N2) { w_xp[i] = (bf16)x_proj_w[i]; return; }
    i -= N2;
    if (i < N3) {
        int row = i >> 6, c = i & 63;
        w_dt[i] = (c < DTRANK) ? (bf16)dt_proj_w[row * DTRANK + c] : (bf16)0.f;
        return;
    }
    i -= N3;
    if (i < N4) { w_out[i] = (bf16)out_proj_w[i]; return; }
    i -= N4;
    if (i < N5) {
        int layer = i / (DSTATE * DI);
        int rem   = i - layer * (DSTATE * DI);
        int n     = rem / DI;
        int d     = rem - n * DI;
        a2T[i] = -__expf(A_log[(size_t)layer * DI * DSTATE + d * DSTATE + n]) * LOG2E;
    }
}

// ---------------------------------------------------------------- rmsnorm -> bf16 (layer 0 only)
__global__ __launch_bounds__(256) void rmsnorm_k(const float* __restrict__ x,
                                                 const float* __restrict__ w,
                                                 bf16* __restrict__ out) {
    int row = blockIdx.x;
    const float* xr = x + (size_t)row * DD;
    int tid = threadIdx.x;
    float v[3]; float ss = 0.f;
    for (int j = 0; j < 3; j++) { v[j] = xr[tid + j * 256]; ss += v[j] * v[j]; }
    for (int o = 1; o < 64; o <<= 1) ss += __shfl_xor(ss, o, 64);
    __shared__ float sred[4];
    if ((tid & 63) == 0) sred[tid >> 6] = ss;
    __syncthreads();
    float scale = rsqrtf((sred[0] + sred[1] + sred[2] + sred[3]) / (float)DD + 1e-6f);
    for (int j = 0; j < 3; j++) {
        int c = tid + j * 256;
        out[(size_t)row * DD + c] = (bf16)(v[j] * scale * w[c]);
    }
}

// ---------------------------------------------------------------- GEMM: C = A @ W^T
// MODE 1: store bf16 | MODE 5: split-K partials f32
template <int MODE>
__global__ __launch_bounds__(256) void gemm_bt(const bf16* __restrict__ A,
                                               const bf16* __restrict__ W,
                                               float* __restrict__ Cf,
                                               bf16* __restrict__ Cb,
                                               int M, int N, int K) {
    __shared__ bf16 As[128][32];
    __shared__ bf16 Ws[128][32];
    const int tid  = threadIdx.x;
    const int m0   = blockIdx.x * 128;
    const int n0   = blockIdx.y * 128;
    const int wave = tid >> 6;
    const int lane = tid & 63;
    const int wm   = (wave >> 1) * 64;
    const int wn   = (wave & 1) * 64;
    const int lrow = lane & 15;
    const int quad = lane >> 4;

    int kbeg = 0, kend = K;
    if constexpr (MODE == 5) {
        int kseg = K / gridDim.z;
        kbeg = blockIdx.z * kseg;
        kend = kbeg + kseg;
        Cf  += (size_t)blockIdx.z * M * N;
    }

    floatx4 acc[4][4];
    for (int mi = 0; mi < 4; mi++)
        for (int ni = 0; ni < 4; ni++) acc[mi][ni] = (floatx4){0.f, 0.f, 0.f, 0.f};

    const int r0  = tid >> 2;        // 0..63
    const int r1  = r0 + 64;         // 64..127
    const int seg = (tid & 3) * 8;   // 0,8,16,24
    char* asb0 = (char*)As + wave * 1024;
    char* asb1 = (char*)As + 4096 + wave * 1024;
    char* wsb0 = (char*)Ws + wave * 1024;
    char* wsb1 = (char*)Ws + 4096 + wave * 1024;

    for (int kb = kbeg; kb < kend; kb += 32) {
        int gk = kb + seg;
        __syncthreads();   // previous iteration's LDS reads done
        ld16(asb0, A + (size_t)(m0 + r0) * K + gk);
        ld16(asb1, A + (size_t)(m0 + r1) * K + gk);
        ld16(wsb0, W + (size_t)(n0 + r0) * K + gk);
        ld16(wsb1, W + (size_t)(n0 + r1) * K + gk);
        wait_vm0();        // this wave's async LDS fills landed
        __syncthreads();   // all waves' fills landed -> tiles ready
        bf16x8 af[4], wf[4];
        for (int mi = 0; mi < 4; mi++) af[mi] = *(const bf16x8*)&As[wm + mi * 16 + lrow][quad * 8];
        for (int ni = 0; ni < 4; ni++) wf[ni] = *(const bf16x8*)&Ws[wn + ni * 16 + lrow][quad * 8];
        for (int mi = 0; mi < 4; mi++)
            for (int ni = 0; ni < 4; ni++)
                acc[mi][ni] = __builtin_amdgcn_mfma_f32_16x16x32_bf16(af[mi], wf[ni], acc[mi][ni], 0, 0, 0);
    }
    for (int mi = 0; mi < 4; mi++) {
        int rowb = m0 + wm + mi * 16 + quad * 4;
        for (int ni = 0; ni < 4; ni++) {
            int col = n0 + wn + ni * 16 + lrow;
            for (int r = 0; r < 4; r++) {
                int row = rowb + r;
                float v = acc[mi][ni][r];
                if constexpr (MODE == 1) Cb[(size_t)row * N + col] = (bf16)v;
                else                     Cf[(size_t)row * N + col] = v;
            }
        }
    }
}

// ---------------------------------------------------------------- out_proj partials + residual + NEXT layer rmsnorm (fused)
__global__ __launch_bounds__(256) void op_reduce_norm_k(const float* __restrict__ part,
                                                        const float* __restrict__ resid,
                                                        const float* __restrict__ nw,
                                                        float* __restrict__ xout,
                                                        bf16* __restrict__ xnb) {
    int row = blockIdx.x;
    int tid = threadIdx.x;
    float v[3]; float ss = 0.f;
    for (int j = 0; j < 3; j++) {
        int c = tid + j * 256;
        size_t idx = (size_t)row * DD + c;
        float s = resid[idx];
        for (int ks = 0; ks < OPKS; ks++) s += part[(size_t)ks * MROWS * DD + idx];
        v[j] = s;
        xout[idx] = s;
        ss += s * s;
    }
    for (int o = 1; o < 64; o <<= 1) ss += __shfl_xor(ss, o, 64);
    __shared__ float sred[4];
    if ((tid & 63) == 0) sred[tid >> 6] = ss;
    __syncthreads();
    float scale = rsqrtf((sred[0] + sred[1] + sred[2] + sred[3]) / (float)DD + 1e-6f);
    for (int j = 0; j < 3; j++) {
        int c = tid + j * 256;
        xnb[(size_t)row * DD + c] = (bf16)(v[j] * scale * nw[c]);
    }
}

// ---------------------------------------------------------------- x_proj split-K GEMM
__global__ __launch_bounds__(256) void gemm_xp(const bf16* __restrict__ A,
                                               const bf16* __restrict__ W,
                                               float* __restrict__ part) {
    __shared__ bf16 As[64][40];
    __shared__ bf16 Ws[128][40];
    const int tid  = threadIdx.x;
    const int m0   = blockIdx.x * 64;
    const int ks   = blockIdx.y;
    const int k0   = ks * (DI / KSPLIT);
    const int wave = tid >> 6;
    const int lane = tid & 63;
    const int lrow = lane & 15;
    const int quad = lane >> 4;
    const int wm   = wave * 16;

    floatx4 acc[5];
    for (int ni = 0; ni < 5; ni++) acc[ni] = (floatx4){0.f, 0.f, 0.f, 0.f};

    const int ra  = tid >> 2;
    const int rw1 = ra + 64;
    const int seg = (tid & 3) * 8;

    for (int kb = 0; kb < DI / KSPLIT; kb += 32) {
        int gk = k0 + kb + seg;
        bf16x8 va = *(const bf16x8*)(A + (size_t)(m0 + ra) * DI + gk);
        bf16x8 vw0, vw1;
        if (ra < NXP) vw0 = *(const bf16x8*)(W + (size_t)ra * DI + gk);
        else          for (int j = 0; j < 8; j++) vw0[j] = (bf16)0.f;
        if (rw1 < NXP) vw1 = *(const bf16x8*)(W + (size_t)rw1 * DI + gk);
        else           for (int j = 0; j < 8; j++) vw1[j] = (bf16)0.f;
        __syncthreads();
        *(bf16x8*)&As[ra][seg]  = va;
        *(bf16x8*)&Ws[ra][seg]  = vw0;
        *(bf16x8*)&Ws[rw1][seg] = vw1;
        __syncthreads();
        bf16x8 af = *(const bf16x8*)&As[wm + lrow][quad * 8];
        for (int ni = 0; ni < 5; ni++) {
            bf16x8 wf = *(const bf16x8*)&Ws[ni * 16 + lrow][quad * 8];
            acc[ni] = __builtin_amdgcn_mfma_f32_16x16x32_bf16(af, wf, acc[ni], 0, 0, 0);
        }
    }
    float* pout = part + (size_t)ks * MROWS * NXP;
    for (int ni = 0; ni < 5; ni++) {
        int col = ni * 16 + lrow;
        for (int r = 0; r < 4; r++) {
            int row = m0 + wm + quad * 4 + r;
            pout[(size_t)row * NXP + col] = acc[ni][r];
        }
    }
}

// reduce split-K partials -> xdbl f32 + padded bf16 dt
__global__ __launch_bounds__(256) void xp_reduce_k(const float* __restrict__ part,
                                                   float* __restrict__ xdbl,
                                                   bf16* __restrict__ dtbf) {
    int idx = blockIdx.x * 256 + threadIdx.x;
    if (idx >= MROWS * NXP) return;
    float s = 0.f;
    for (int j = 0; j < KSPLIT; j++) s += part[(size_t)j * MROWS * NXP + idx];
    xdbl[idx] = s;
    int m = idx / NXP, c = idx - m * NXP;
    if (c < DTRANK)      dtbf[m * DTPAD + c] = (bf16)s;
    else if (c < DTPAD)  dtbf[m * DTPAD + c] = (bf16)0.f;
}

// ---------------------------------------------------------------- causal depthwise conv + silu + gate (4-wide, bf16 outputs)
__global__ __launch_bounds__(256) void conv_silu_k(const bf16* __restrict__ xz,
                                                   const float* __restrict__ cw,
                                                   const float* __restrict__ cb,
                                                   bf16* __restrict__ xcb,
                                                   bf16* __restrict__ gzb) {
    int t = blockIdx.x * 256 + threadIdx.x;
    if (t >= MROWS * (DI / 4)) return;
    int m = t / (DI / 4);
    int d = (t - m * (DI / 4)) * 4;
    int l = m & (LL - 1);
    float acc[4];
    floatx4 cwv[4];
    for (int q = 0; q < 4; q++) {
        acc[q] = cb[d + q];
        cwv[q] = *(const floatx4*)&cw[(d + q) * 4];
    }
    for (int k = 0; k < 4; k++) {
        int lp = l - 3 + k;
        if (lp >= 0) {
            bf16x4 v = *(const bf16x4*)&xz[(size_t)(m - 3 + k) * (2 * DI) + d];
            for (int q = 0; q < 4; q++) acc[q] += (float)v[q] * cwv[q][k];
        }
    }
    bf16x4 xo, go;
    bf16x4 z4 = *(const bf16x4*)&xz[(size_t)m * (2 * DI) + DI + d];
    for (int q = 0; q < 4; q++) {
        float s = acc[q] / (1.f + __expf(-acc[q]));
        xo[q] = (bf16)s;
        float zv = (float)z4[q];
        go[q] = (bf16)(zv / (1.f + __expf(-zv)));
    }
    *(bf16x4*)&xcb[(size_t)m * DI + d] = xo;
    *(bf16x4*)&gzb[(size_t)m * DI + d] = go;
}

// ---------------------------------------------------------------- selective scan v8 (scanB)
// v7 post-mortem: inner loop charged ~15 slots per (d,n,step) — 8-op DPP
// butterfly + per-(n) operand handling around 2 ops of real work. v8: each
// lane owns (d, 4 consecutive n) with h[4] in registers. Per step: 4x state
// update, in-register C-dot, 2-op quad DPP reduce, one float4 B + C read.
// ~30 slots per step / 4 (d,n) = 7.5 per (d,n). Block = 64 d x 4 quads; grid
// (DI/64, BB, NC) = 768 blocks = 3072 waves = 3/SIMD ALL RESIDENT (LDS 35.8K
// -> 4 blocks/CU). One barrier total: pack is register-MFMA -> LDS, xc DMA
// drains under it, single sync, scan, direct global emit of ylsc/P/S.
__global__ __launch_bounds__(256) void scanB_k(const bf16* __restrict__ dtb,
                                               const bf16* __restrict__ wdt,
                                               const float* __restrict__ dtbias,
                                               const bf16* __restrict__ xcb,
                                               const float* __restrict__ xdbl,
                                               const float* __restrict__ A_log,
                                               float* __restrict__ Pbuf,
                                               float* __restrict__ Sbuf,
                                               float2* __restrict__ ylsc) {
    const int b   = blockIdx.y;
    const int d0  = blockIdx.x * DBLK;
    const int c   = blockIdx.z;
    const int tid = threadIdx.x;
    const int wv  = tid >> 6;
    const int lane = tid & 63;
    const int lr  = lane & 15;
    const int q   = lane >> 4;
    const int l0  = c * CLEN;
    const int dl  = tid >> 2;          // 0..63: d within block (scan phase)
    const int nq  = tid & 3;           // n-quad (aligned with DPP quads)

    __shared__ __align__(16) float sdp[DBLK][68];      // [d][l] dv  (17.4 KB)
    __shared__ __align__(16) bf16  sxc[CLEN][DBLK];    // [l][d] conv out, DMA (8 KB)
    __shared__ __align__(16) float sB[CLEN][20];       // [l][n] B (5.1 KB)
    __shared__ __align__(16) float sC[CLEN][20];       // [l][n] C (5.1 KB)

    // ---- stage: xc via DMA (drains under pack) ----
    {
        int t2 = tid;
        ld16((char*)&sxc[0][0] + (t2 & ~63) * 16,
             xcb + (size_t)(b * LL + l0 + (t2 >> 3)) * DI + d0 + (t2 & 7) * 8);
        t2 = tid + 256;
        ld16((char*)&sxc[0][0] + (t2 & ~63) * 16,
             xcb + (size_t)(b * LL + l0 + (t2 >> 3)) * DI + d0 + (t2 & 7) * 8);
    }

    // ---- B/C: global regs -> transposed LDS ----
    {
        float Bv[4], Cv[4];
        #pragma unroll
        for (int k2 = 0; k2 < 4; ++k2) {
            int ii = (tid + 256 * k2) >> 4;
            const float* p = &xdbl[(size_t)(b * LL + l0 + ii) * NXP + DTRANK + (tid & 15)];
            Bv[k2] = p[0];
            Cv[k2] = p[DSTATE];
        }
        #pragma unroll
        for (int k2 = 0; k2 < 4; ++k2) {
            int ii = (tid + 256 * k2) >> 4;
            sB[ii][tid & 15] = Bv[k2];
            sC[ii][tid & 15] = Cv[k2];
        }
    }

    // ---- per-thread a2[4] for (d, 4 n) ----
    float4 a2q;
    {
        float4 al = *(const float4*)&A_log[(size_t)(d0 + dl) * DSTATE + nq * 4];
        a2q.x = -__expf(al.x) * LOG2E;
        a2q.y = -__expf(al.y) * LOG2E;
        a2q.z = -__expf(al.z) * LOG2E;
        a2q.w = -__expf(al.w) * LOG2E;
    }

    // ---- pack: delta = softplus(dt @ w_dt^T + bias) via MFMA, regs only -> sdp ----
    {
        const bf16* ar = &dtb[(size_t)(b * LL + l0 + 16 * wv + lr) * DTPAD + q * 8];
        bf16x8 a0 = *(const bf16x8*)ar;
        bf16x8 a1 = *(const bf16x8*)(ar + 32);
        #pragma unroll
        for (int j = 0; j < 4; ++j) {
            const bf16* wr = &wdt[(size_t)(d0 + 16 * j + lr) * DTPAD + q * 8];
            bf16x8 w0 = *(const bf16x8*)wr;
            bf16x8 w1 = *(const bf16x8*)(wr + 32);
            floatx4 dacc = (floatx4){0.f, 0.f, 0.f, 0.f};
            dacc = __builtin_amdgcn_mfma_f32_16x16x32_bf16(a0, w0, dacc, 0, 0, 0);
            dacc = __builtin_amdgcn_mfma_f32_16x16x32_bf16(a1, w1, dacc, 0, 0, 0);
            float bi = dtbias[d0 + 16 * j + lr];
            #pragma unroll
            for (int r = 0; r < 4; ++r) {
                int l = 16 * wv + q * 4 + r;
                sdp[16 * j + lr][l] = softplus_fast(dacc[r] + bi);
            }
        }
    }

    wait_vm0();        // sxc DMA landed (hidden under pack)
    __syncthreads();   // the kernel's single barrier

    // ---- 64-step scan: h[4] in regs, quad DPP y-reduce, direct global emit ----
    {
        float4 hq = make_float4(0.f, 0.f, 0.f, 0.f);
        float sdc = 0.f;
        const float* dvrow = &sdp[dl][0];
        const unsigned short* xcp = (const unsigned short*)&sxc[0][0] + dl;
        for (int g = 0; g < 16; ++g) {
            float4 dvv = *(const float4*)&dvrow[4 * g];
            float2 yst[4];
            #pragma unroll
            for (int i2 = 0; i2 < 4; ++i2) {
                int i = 4 * g + i2;
                float dv = (i2 == 0) ? dvv.x : (i2 == 1) ? dvv.y : (i2 == 2) ? dvv.z : dvv.w;
                float xcv = __int_as_float((unsigned)xcp[i * DBLK] << 16);
                float du = dv * xcv;
                float4 Bq = *(const float4*)&sB[i][4 * nq];
                float4 Cq = *(const float4*)&sC[i][4 * nq];
                hq.x = __builtin_fmaf(exp2_raw(a2q.x * dv), hq.x, du * Bq.x);
                hq.y = __builtin_fmaf(exp2_raw(a2q.y * dv), hq.y, du * Bq.y);
                hq.z = __builtin_fmaf(exp2_raw(a2q.z * dv), hq.z, du * Bq.z);
                hq.w = __builtin_fmaf(exp2_raw(a2q.w * dv), hq.w, du * Bq.w);
                float y = __builtin_fmaf(Cq.w, hq.w,
                          __builtin_fmaf(Cq.z, hq.z,
                          __builtin_fmaf(Cq.y, hq.y, Cq.x * hq.x)));
                y = quad4_sum(y);
                sdc += dv;
                yst[i2] = make_float2(y, sdc);
            }
            if (nq == 0) {
                size_t base = (size_t)(b * LL + l0 + 4 * g) * DI + d0 + dl;
                ylsc[base]          = yst[0];
                ylsc[base + DI]     = yst[1];
                ylsc[base + 2 * DI] = yst[2];
                ylsc[base + 3 * DI] = yst[3];
            }
        }
        // chunk (P, S) per (d, n): float4 per thread, fully coalesced
        float4 Pq;
        Pq.x = exp2_raw(a2q.x * sdc);
        Pq.y = exp2_raw(a2q.y * sdc);
        Pq.z = exp2_raw(a2q.z * sdc);
        Pq.w = exp2_raw(a2q.w * sdc);
        size_t o = (((size_t)c * BB + b) * DI + (d0 + dl)) * DSTATE + nq * 4;
        *(float4*)&Pbuf[o] = Pq;
        *(float4*)&Sbuf[o] = make_float4(hq.x, hq.y, hq.z, hq.w);
    }
}

// Prefix-compose (P,S) over chunks -> H0T[c][n][d] = h entering chunk c (transposed).
__global__ __launch_bounds__(256) void compose_k(const float* __restrict__ P,
                                                 const float* __restrict__ S,
                                                 float* __restrict__ H0T) {
    int idx = blockIdx.x * 256 + threadIdx.x;   // over BB*DI*DSTATE, (b,d,n) order
    const size_t stride = (size_t)BB * DI * DSTATE;
    int b = idx / (DI * DSTATE);
    int rest = idx - b * (DI * DSTATE);
    int d = rest >> 4;
    int n = rest & 15;
    float h = 0.f;
    #pragma unroll
    for (int c = 0; c < NC; ++c) {
        H0T[((size_t)c * BB + b) * (DSTATE * DI) + (size_t)n * DI + d] = h;
        h = __builtin_fmaf(P[(size_t)c * stride + idx], h, S[(size_t)c * stride + idx]);
    }
}

// Parallel correction: y = (yloc + sum_n C*exp2(a2*Scum)*h0 + xc*D) * gz.
// grid (24, BB, NC); thread handles 4 l's (stride 16 in chunk) x 4 consecutive d.
__global__ __launch_bounds__(256) void corr_k(const float2* __restrict__ ylsc,
                                              const float* __restrict__ xdbl,
                                              const float* __restrict__ H0T,
                                              const float* __restrict__ a2T,
                                              const bf16* __restrict__ xcb,
                                              const bf16* __restrict__ gzb,
                                              const float* __restrict__ Dskip,
                                              bf16* __restrict__ ybf) {
    const int b = blockIdx.y, c = blockIdx.z;
    const int tid = threadIdx.x;
    const int t6 = blockIdx.x * 256 + tid;        // 0..6143
    const int dq   = (t6 % 384) * 4;              // d quad
    const int loff = t6 / 384;                    // 0..15

    __shared__ __align__(16) float sC[CLEN][16];  // C tile (d-independent)
    {
        int l = tid >> 2, nn = (tid & 3) * 4;
        *(float4*)&sC[l][nn] =
            *(const float4*)&xdbl[(size_t)(b * LL + c * CLEN + l) * NXP + DTRANK + DSTATE + nn];
    }
    __syncthreads();

    const float* h0base = H0T + ((size_t)c * BB + b) * (DSTATE * DI);
    int m0_ = b * LL + c * CLEN + loff;
    floatx4 acc[4];
    float4 sc[4];
    #pragma unroll
    for (int s = 0; s < 4; ++s) {
        size_t mo = (size_t)(m0_ + s * 16) * DI + dq;
        float4 u0 = *(const float4*)&ylsc[mo];       // (yl0,sc0,yl1,sc1)
        float4 u1 = *(const float4*)&ylsc[mo + 2];   // (yl2,sc2,yl3,sc3)
        acc[s] = (floatx4){u0.x, u0.z, u1.x, u1.z};
        sc[s]  = make_float4(u0.y, u0.w, u1.y, u1.w);
    }
    #pragma unroll
    for (int n = 0; n < DSTATE; ++n) {
        float4 a2v = *(const float4*)&a2T[(size_t)n * DI + dq];
        float4 h0v = *(const float4*)&h0base[(size_t)n * DI + dq];
        #pragma unroll
        for (int s = 0; s < 4; ++s) {
            float Cn = sC[loff + s * 16][n];
            acc[s][0] = __builtin_fmaf(Cn * h0v.x, exp2_raw(a2v.x * sc[s].x), acc[s][0]);
            acc[s][1] = __builtin_fmaf(Cn * h0v.y, exp2_raw(a2v.y * sc[s].y), acc[s][1]);
            acc[s][2] = __builtin_fmaf(Cn * h0v.z, exp2_raw(a2v.z * sc[s].z), acc[s][2]);
            acc[s][3] = __builtin_fmaf(Cn * h0v.w, exp2_raw(a2v.w * sc[s].w), acc[s][3]);
        }
    }
    float4 Dsk = *(const float4*)&Dskip[dq];
    #pragma unroll
    for (int s = 0; s < 4; ++s) {
        size_t mo = (size_t)(m0_ + s * 16) * DI + dq;
        bf16x4 xc4 = *(const bf16x4*)&xcb[mo];
        bf16x4 gz4 = *(const bf16x4*)&gzb[mo];
        bf16x4 yo;
        yo[0] = (bf16)((acc[s][0] + (float)xc4[0] * Dsk.x) * (float)gz4[0]);
        yo[1] = (bf16)((acc[s][1] + (float)xc4[1] * Dsk.y) * (float)gz4[1]);
        yo[2] = (bf16)((acc[s][2] + (float)xc4[2] * Dsk.z) * (float)gz4[2]);
        yo[3] = (bf16)((acc[s][3] + (float)xc4[3] * Dsk.w) * (float)gz4[3]);
        *(bf16x4*)&ybf[mo] = yo;
    }
}

// ---------------------------------------------------------------- head
__global__ __launch_bounds__(256) void head_norm_k(const float* __restrict__ x,
                                                   const float* __restrict__ fnw,
                                                   float* __restrict__ xn_buf) {
    int b = blockIdx.x;
    int tid = threadIdx.x;
    const float* xr = x + ((size_t)b * LL + (LL - 1)) * DD;
    __shared__ float sred[4];
    float v[3]; float ss = 0.f;
    for (int j = 0; j < 3; j++) { v[j] = xr[tid + j * 256]; ss += v[j] * v[j]; }
    for (int o = 1; o < 64; o <<= 1) ss += __shfl_xor(ss, o, 64);
    if ((tid & 63) == 0) sred[tid >> 6] = ss;
    __syncthreads();
    float scale = rsqrtf((sred[0] + sred[1] + sred[2] + sred[3]) / (float)DD + 1e-6f);
    for (int j = 0; j < 3; j++) {
        int c = tid + j * 256;
        xn_buf[(size_t)b * DD + c] = v[j] * scale * fnw[c];
    }
}

__global__ __launch_bounds__(256) void head_h1_k(const float* __restrict__ xn_buf,
                                                 const float* __restrict__ h1w,
                                                 const float* __restrict__ h1b,
                                                 float* __restrict__ h_buf) {
    int b  = blockIdx.x;
    int o0 = blockIdx.y * 64;
    int tid = threadIdx.x;
    __shared__ float sx[DD];
    for (int c = tid; c < DD; c += 256) sx[c] = xn_buf[(size_t)b * DD + c];
    __syncthreads();
    int wave = tid >> 6, lane = tid & 63;
    for (int j = 0; j < 16; j++) {
        int o = o0 + wave * 16 + j;
        const float* wrow = h1w + (size_t)o * DD;
        float acc = 0.f;
        for (int k = 0; k < 12; k++) {
            int c = lane + 64 * k;
            acc += wrow[c] * sx[c];
        }
        for (int off = 1; off < 64; off <<= 1) acc += __shfl_xor(acc, off, 64);
        if (lane == 0) h_buf[(size_t)b * DD + o] = acc + h1b[o];
    }
}

__global__ __launch_bounds__(256) void head_out_k(const float* __restrict__ h_buf,
                                                  const float* __restrict__ hnw,
                                                  const float* __restrict__ h2w,
                                                  const float* __restrict__ h2b,
                                                  float* __restrict__ out) {
    int b = blockIdx.x;
    int tid = threadIdx.x;
    __shared__ float hh[DD];
    __shared__ float sred[4];
    const float* hr = h_buf + (size_t)b * DD;
    float ss = 0.f;
    for (int c = tid; c < DD; c += 256) { float v = hr[c]; ss += v * v; }
    for (int o = 1; o < 64; o <<= 1) ss += __shfl_xor(ss, o, 64);
    if ((tid & 63) == 0) sred[tid >> 6] = ss;
    __syncthreads();
    float sc = rsqrtf((sred[0] + sred[1] + sred[2] + sred[3]) / (float)DD + 1e-6f);
    for (int c = tid; c < DD; c += 256) {
        float v = hr[c] * sc * hnw[c];
        hh[c] = 0.5f * v * (1.f + erff(v * 0.70710678118f));
    }
    __syncthreads();
    int w = tid >> 6, lane = tid & 63;
    for (int j = w; j < 10; j += 4) {
        float acc = 0.f;
        const float* wrow = h2w + (size_t)j * DD;
        for (int c = lane; c < DD; c += 64) acc += hh[c] * wrow[c];
        for (int o = 1; o < 64; o <<= 1) acc += __shfl_xor(acc, o, 64);
        if (lane == 0) out[b * 10 + j] = acc + h2b[j];
    }
}

// ----------------------------------------------------------------
extern "C" void kernel_launch(void* const* d_in, const int* in_sizes, int n_in,
                              void* d_out, int out_size, void* d_ws, size_t ws_size,
                              hipStream_t stream) {
    const float* x_in      = (const float*)d_in[0];
    const float* norm_w    = (const float*)d_in[1];
    const float* in_proj_w = (const float*)d_in[2];
    const float* conv_w    = (const float*)d_in[3];
    const float* conv_b    = (const float*)d_in[4];
    const float* x_proj_w  = (const float*)d_in[5];
    const float* dt_proj_w = (const float*)d_in[6];
    const float* dt_proj_b = (const float*)d_in[7];
    const float* A_log     = (const float*)d_in[8];
    const float* D_skip    = (const float*)d_in[9];
    const float* out_proj_w= (const float*)d_in[10];
    const float* fnw       = (const float*)d_in[11];
    const float* h1w       = (const float*)d_in[12];
    const float* h1b       = (const float*)d_in[13];
    const float* hnw       = (const float*)d_in[14];
    const float* h2w       = (const float*)d_in[15];
    const float* h2b       = (const float*)d_in[16];
    float* out = (float*)d_out;

    char* ws = (char*)d_ws;
    size_t off = 0;
    auto alloc = [&](size_t bytes) -> void* {
        void* p = ws + off;
        off += (bytes + 255) & ~(size_t)255;
        return p;
    };
    bf16* w_in  = (bf16*)alloc((size_t)N1 * 2);
    bf16* w_xp  = (bf16*)alloc((size_t)N2 * 2);
    bf16* w_dt  = (bf16*)alloc((size_t)N3 * 2);
    bf16* w_out = (bf16*)alloc((size_t)N4 * 2);
    float* a2T  = (float*)alloc((size_t)N5 * 4);
    bf16* xn_bf = (bf16*)alloc((size_t)MROWS * DD * 2);
    bf16* xz_bf = (bf16*)alloc((size_t)MROWS * 2 * DI * 2);
    bf16* xc_bf = (bf16*)alloc((size_t)MROWS * DI * 2);
    bf16* gz_bf = (bf16*)alloc((size_t)MROWS * DI * 2);
    float* xdbl = (float*)alloc((size_t)MROWS * NXP * 4);
    bf16* dt_bf = (bf16*)alloc((size_t)MROWS * DTPAD * 2);
    bf16* y_bf  = (bf16*)alloc((size_t)MROWS * DI * 2);
    float* x_buf= (float*)alloc((size_t)MROWS * DD * 4);
    float* Pbuf = (float*)alloc((size_t)NC * BB * DI * DSTATE * 4);
    float* Sbuf = (float*)alloc((size_t)NC * BB * DI * DSTATE * 4);
    float* H0T  = (float*)alloc((size_t)NC * BB * DI * DSTATE * 4);
    float2* ylsc= (float2*)alloc((size_t)MROWS * DI * 8);
    float* xnl  = (float*)alloc((size_t)BB * DD * 4);
    float* hbuf = (float*)alloc((size_t)BB * DD * 4);
    float* xp_part = (float*)alloc((size_t)KSPLIT * MROWS * NXP * 4);
    float* op_part = (float*)alloc((size_t)OPKS * MROWS * DD * 4);

    // all weight conversions + a2T table in one launch
    {
        int ntot = N1 + N2 + N3 + N4 + N5;
        cvt_all_k<<<(ntot + 255) / 256, 256, 0, stream>>>(
            in_proj_w, x_proj_w, dt_proj_w, out_proj_w, A_log,
            w_in, w_xp, w_dt, w_out, a2T);
    }

    for (int i = 0; i < 4; i++) {
        const float* x_src = (i == 0) ? x_in : x_buf;
        // 1. rmsnorm (layer 0 only; later layers get xn_bf from fused op_reduce_norm)
        if (i == 0)
            rmsnorm_k<<<MROWS, 256, 0, stream>>>(x_src, norm_w, xn_bf);
        // 2. in_proj: (2048 x 3072), bf16 out
        gemm_bt<1><<<dim3(MROWS / 128, 3072 / 128), 256, 0, stream>>>(
            xn_bf, w_in + (size_t)i * 3072 * 768, nullptr, xz_bf,
            MROWS, 2 * DI, DD);
        // 3. causal conv + silu + silu(z) gate (bf16 outputs)
        conv_silu_k<<<(MROWS * (DI / 4) + 255) / 256, 256, 0, stream>>>(
            xz_bf, conv_w + (size_t)i * DI * 4, conv_b + (size_t)i * DI, xc_bf, gz_bf);
        // 4. x_proj split-K + reduce -> xdbl f32 + padded bf16 dt
        gemm_xp<<<dim3(MROWS / 64, KSPLIT), 256, 0, stream>>>(
            xc_bf, w_xp + (size_t)i * NXP * DI, xp_part);
        xp_reduce_k<<<(MROWS * NXP + 255) / 256, 256, 0, stream>>>(xp_part, xdbl, dt_bf);
        // 5. scan v8: 4-state lanes, all-resident grid -> compose -> parallel corr
        scanB_k<<<dim3(DI / DBLK, BB, NC), 256, 0, stream>>>(
            dt_bf, w_dt + (size_t)i * DI * DTPAD, dt_proj_b + (size_t)i * DI,
            xc_bf, xdbl, A_log + (size_t)i * DI * DSTATE, Pbuf, Sbuf, ylsc);
        compose_k<<<(BB * DI * DSTATE) / 256, 256, 0, stream>>>(Pbuf, Sbuf, H0T);
        corr_k<<<dim3(24, BB, NC), 256, 0, stream>>>(
            ylsc, xdbl, H0T, a2T + (size_t)i * DSTATE * DI,
            xc_bf, gz_bf, D_skip + (size_t)i * DI, y_bf);
        // 6. out_proj split-K -> partials; fused reduce + residual + next rmsnorm
        gemm_bt<5><<<dim3(MROWS / 128, DD / 128, OPKS), 256, 0, stream>>>(
            y_bf, w_out + (size_t)i * DD * DI, op_part, nullptr,
            MROWS, DD, DI);
        op_reduce_norm_k<<<MROWS, 256, 0, stream>>>(
            op_part, x_src, norm_w + ((i + 1) & 3) * DD, x_buf, xn_bf);
    }

    head_norm_k<<<BB, 256, 0, stream>>>(x_buf, fnw, xnl);
    head_h1_k<<<dim3(BB, DD / 64), 256, 0, stream>>>(xnl, h1w, h1b, hbuf);
    head_out_k<<<BB, 256, 0, stream>>>(hbuf, hnw, h2w, h2b, out);
}

// Round 9
// 582.254 us; speedup vs baseline: 1.1521x; 1.0221x over previous
//
#include <hip/hip_runtime.h>
#include <hip/hip_bf16.h>
#include <math.h>

typedef __bf16 bf16;
typedef __bf16 bf16x4 __attribute__((ext_vector_type(4)));
typedef __bf16 bf16x8 __attribute__((ext_vector_type(8)));
typedef float floatx4 __attribute__((ext_vector_type(4)));

#define BB 2
#define LL 1024
#define DD 768
#define DI 1536
#define MROWS 2048   // B*L
#define NXP 80       // dt_rank + 2*d_state
#define DTRANK 48
#define DTPAD 64     // dt K padded to 64
#define DSTATE 16
#define NC 16        // scan chunks
#define CLEN 64      // scan chunk length (NC*CLEN == LL)
#define DBLK 64      // scan d-columns per block (v8)
#define KSPLIT 16    // x_proj split-K factor (K-seg = 96)
#define OPKS 4       // out_proj split-K factor (K-seg = 384)
#define LOG2E 1.4426950408889634f
#define LN2   0.6931471805599453f

// async global->LDS, 16 B per lane; lds dest must be wave-uniform base (+lane*16)
__device__ __forceinline__ void ld16(void* lds, const void* g) {
    __builtin_amdgcn_global_load_lds(
        (const __attribute__((address_space(1))) void*)g,
        (__attribute__((address_space(3))) void*)lds, 16, 0, 0);
}

// drain this wave's outstanding async global_load_lds before signalling barrier.
__device__ __forceinline__ void wait_vm0() {
    asm volatile("s_waitcnt vmcnt(0)" ::: "memory");
}

// 4-lane quad sum via DPP quad_perm (lanes grouped by lane[1:0]): all 4 get the sum.
__device__ __forceinline__ float quad4_sum(float x) {
    float t;
    t = __int_as_float(__builtin_amdgcn_update_dpp(0, __float_as_int(x), 0xB1, 0xF, 0xF, true)); x += t; // xor1
    t = __int_as_float(__builtin_amdgcn_update_dpp(0, __float_as_int(x), 0x4E, 0xF, 0xF, true)); x += t; // xor2
    return x;
}

// raw v_exp_f32 / v_log_f32 (no ocml denormal fixup)
__device__ __forceinline__ float exp2_raw(float x) {
#if __has_builtin(__builtin_amdgcn_exp2f)
    return __builtin_amdgcn_exp2f(x);
#else
    float r; asm("v_exp_f32 %0, %1" : "=v"(r) : "v"(x)); return r;
#endif
}
__device__ __forceinline__ float log2_raw(float x) {
#if __has_builtin(__builtin_amdgcn_logf)
    return __builtin_amdgcn_logf(x);
#else
    float r; asm("v_log_f32 %0, %1" : "=v"(r) : "v"(x)); return r;
#endif
}
// softplus(v) = ln(1+exp(v)) via raw exp2/log2; guard large v (exp2 overflow).
__device__ __forceinline__ float softplus_fast(float v) {
    float t  = exp2_raw(v * LOG2E);
    float sp = log2_raw(1.f + t) * LN2;
    return (v > 20.f) ? v : sp;
}

// ---------------------------------------------------------------- all weight cvt in one kernel
#define N1 (4 * 3072 * 768)
#define N2 (4 * NXP * DI)
#define N3 (4 * DI * DTPAD)
#define N4 (4 * DD * DI)
#define N5 (4 * DSTATE * DI)   // a2T[layer][n][d] = -exp(A_log[layer,d,n])*log2(e)
__global__ __launch_bounds__(256) void cvt_all_k(const float* __restrict__ in_proj_w,
                                                 const float* __restrict__ x_proj_w,
                                                 const float* __restrict__ dt_proj_w,
                                                 const float* __restrict__ out_proj_w,
                                                 const float* __restrict__ A_log,
                                                 bf16* __restrict__ w_in,
                                                 bf16* __restrict__ w_xp,
                                                 bf16* __restrict__ w_dt,
                                                 bf16* __restrict__ w_out,
                                                 float* __restrict__ a2T) {
    int i = blockIdx.x * 256 + threadIdx.x;
    if (i < N1) { w_in[i] = (bf16)in_proj_w[i]; return; }
    i -= N1;
    if (i < N2) { w_xp[i] = (bf16)x_proj_w[i]; return; }
    i -= N2;
    if (i < N3) {
        int row = i >> 6, c = i & 63;
        w_dt[i] = (c < DTRANK) ? (bf16)dt_proj_w[row * DTRANK + c] : (bf16)0.f;
        return;
    }
    i -= N3;
    if (i < N4) { w_out[i] = (bf16)out_proj_w[i]; return; }
    i -= N4;
    if (i < N5) {
        int layer = i / (DSTATE * DI);
        int rem   = i - layer * (DSTATE * DI);
        int n     = rem / DI;
        int d     = rem - n * DI;
        a2T[i] = -__expf(A_log[(size_t)layer * DI * DSTATE + d * DSTATE + n]) * LOG2E;
    }
}

// ---------------------------------------------------------------- rmsnorm -> bf16 (layer 0 only)
__global__ __launch_bounds__(256) void rmsnorm_k(const float* __restrict__ x,
                                                 const float* __restrict__ w,
                                                 bf16* __restrict__ out) {
    int row = blockIdx.x;
    const float* xr = x + (size_t)row * DD;
    int tid = threadIdx.x;
    float v[3]; float ss = 0.f;
    for (int j = 0; j < 3; j++) { v[j] = xr[tid + j * 256]; ss += v[j] * v[j]; }
    for (int o = 1; o < 64; o <<= 1) ss += __shfl_xor(ss, o, 64);
    __shared__ float sred[4];
    if ((tid & 63) == 0) sred[tid >> 6] = ss;
    __syncthreads();
    float scale = rsqrtf((sred[0] + sred[1] + sred[2] + sred[3]) / (float)DD + 1e-6f);
    for (int j = 0; j < 3; j++) {
        int c = tid + j * 256;
        out[(size_t)row * DD + c] = (bf16)(v[j] * scale * w[c]);
    }
}

// ---------------------------------------------------------------- GEMM: C = A @ W^T
// MODE 1: store bf16 | MODE 5: split-K partials f32
// TM: M-tile rows (128 = classic 4-wave 128x128; 64 = 64x128, 2x block count
// for short-K TLP-starved shapes — v9: grids become 768 blocks = 3/CU exact).
template <int MODE, int TM>
__global__ __launch_bounds__(256) void gemm_bt(const bf16* __restrict__ A,
                                               const bf16* __restrict__ W,
                                               float* __restrict__ Cf,
                                               bf16* __restrict__ Cb,
                                               int M, int N, int K) {
    constexpr int NI = (TM == 128) ? 4 : 2;   // col-frags per wave
    __shared__ bf16 As[TM][32];
    __shared__ bf16 Ws[128][32];
    const int tid  = threadIdx.x;
    const int m0   = blockIdx.x * TM;
    const int n0   = blockIdx.y * 128;
    const int wave = tid >> 6;
    const int lane = tid & 63;
    const int wm   = (TM == 128) ? (wave >> 1) * 64 : 0;
    const int wn   = (TM == 128) ? (wave & 1) * 64 : wave * 32;
    const int lrow = lane & 15;
    const int quad = lane >> 4;

    int kbeg = 0, kend = K;
    if constexpr (MODE == 5) {
        int kseg = K / gridDim.z;
        kbeg = blockIdx.z * kseg;
        kend = kbeg + kseg;
        Cf  += (size_t)blockIdx.z * M * N;
    }

    floatx4 acc[4][NI];
    for (int mi = 0; mi < 4; mi++)
        for (int ni = 0; ni < NI; ni++) acc[mi][ni] = (floatx4){0.f, 0.f, 0.f, 0.f};

    const int r0  = tid >> 2;        // 0..63
    const int r1  = r0 + 64;         // 64..127
    const int seg = (tid & 3) * 8;   // 0,8,16,24
    char* asb0 = (char*)As + wave * 1024;
    char* asb1 = (char*)As + 4096 + wave * 1024;  // only used when TM==128
    char* wsb0 = (char*)Ws + wave * 1024;
    char* wsb1 = (char*)Ws + 4096 + wave * 1024;

    for (int kb = kbeg; kb < kend; kb += 32) {
        int gk = kb + seg;
        __syncthreads();   // previous iteration's LDS reads done
        ld16(asb0, A + (size_t)(m0 + r0) * K + gk);
        if constexpr (TM == 128)
            ld16(asb1, A + (size_t)(m0 + r1) * K + gk);
        ld16(wsb0, W + (size_t)(n0 + r0) * K + gk);
        ld16(wsb1, W + (size_t)(n0 + r1) * K + gk);
        wait_vm0();        // this wave's async LDS fills landed
        __syncthreads();   // all waves' fills landed -> tiles ready
        bf16x8 af[4], wf[NI];
        for (int mi = 0; mi < 4; mi++) af[mi] = *(const bf16x8*)&As[wm + mi * 16 + lrow][quad * 8];
        for (int ni = 0; ni < NI; ni++) wf[ni] = *(const bf16x8*)&Ws[wn + ni * 16 + lrow][quad * 8];
        for (int mi = 0; mi < 4; mi++)
            for (int ni = 0; ni < NI; ni++)
                acc[mi][ni] = __builtin_amdgcn_mfma_f32_16x16x32_bf16(af[mi], wf[ni], acc[mi][ni], 0, 0, 0);
    }
    for (int mi = 0; mi < 4; mi++) {
        int rowb = m0 + wm + mi * 16 + quad * 4;
        for (int ni = 0; ni < NI; ni++) {
            int col = n0 + wn + ni * 16 + lrow;
            for (int r = 0; r < 4; r++) {
                int row = rowb + r;
                float v = acc[mi][ni][r];
                if constexpr (MODE == 1) Cb[(size_t)row * N + col] = (bf16)v;
                else                     Cf[(size_t)row * N + col] = v;
            }
        }
    }
}

// ---------------------------------------------------------------- out_proj partials + residual + NEXT layer rmsnorm (fused)
__global__ __launch_bounds__(256) void op_reduce_norm_k(const float* __restrict__ part,
                                                        const float* __restrict__ resid,
                                                        const float* __restrict__ nw,
                                                        float* __restrict__ xout,
                                                        bf16* __restrict__ xnb) {
    int row = blockIdx.x;
    int tid = threadIdx.x;
    float v[3]; float ss = 0.f;
    for (int j = 0; j < 3; j++) {
        int c = tid + j * 256;
        size_t idx = (size_t)row * DD + c;
        float s = resid[idx];
        for (int ks = 0; ks < OPKS; ks++) s += part[(size_t)ks * MROWS * DD + idx];
        v[j] = s;
        xout[idx] = s;
        ss += s * s;
    }
    for (int o = 1; o < 64; o <<= 1) ss += __shfl_xor(ss, o, 64);
    __shared__ float sred[4];
    if ((tid & 63) == 0) sred[tid >> 6] = ss;
    __syncthreads();
    float scale = rsqrtf((sred[0] + sred[1] + sred[2] + sred[3]) / (float)DD + 1e-6f);
    for (int j = 0; j < 3; j++) {
        int c = tid + j * 256;
        xnb[(size_t)row * DD + c] = (bf16)(v[j] * scale * nw[c]);
    }
}

// ---------------------------------------------------------------- x_proj split-K GEMM
__global__ __launch_bounds__(256) void gemm_xp(const bf16* __restrict__ A,
                                               const bf16* __restrict__ W,
                                               float* __restrict__ part) {
    __shared__ bf16 As[64][40];
    __shared__ bf16 Ws[128][40];
    const int tid  = threadIdx.x;
    const int m0   = blockIdx.x * 64;
    const int ks   = blockIdx.y;
    const int k0   = ks * (DI / KSPLIT);
    const int wave = tid >> 6;
    const int lane = tid & 63;
    const int lrow = lane & 15;
    const int quad = lane >> 4;
    const int wm   = wave * 16;

    floatx4 acc[5];
    for (int ni = 0; ni < 5; ni++) acc[ni] = (floatx4){0.f, 0.f, 0.f, 0.f};

    const int ra  = tid >> 2;
    const int rw1 = ra + 64;
    const int seg = (tid & 3) * 8;

    for (int kb = 0; kb < DI / KSPLIT; kb += 32) {
        int gk = k0 + kb + seg;
        bf16x8 va = *(const bf16x8*)(A + (size_t)(m0 + ra) * DI + gk);
        bf16x8 vw0, vw1;
        if (ra < NXP) vw0 = *(const bf16x8*)(W + (size_t)ra * DI + gk);
        else          for (int j = 0; j < 8; j++) vw0[j] = (bf16)0.f;
        if (rw1 < NXP) vw1 = *(const bf16x8*)(W + (size_t)rw1 * DI + gk);
        else           for (int j = 0; j < 8; j++) vw1[j] = (bf16)0.f;
        __syncthreads();
        *(bf16x8*)&As[ra][seg]  = va;
        *(bf16x8*)&Ws[ra][seg]  = vw0;
        *(bf16x8*)&Ws[rw1][seg] = vw1;
        __syncthreads();
        bf16x8 af = *(const bf16x8*)&As[wm + lrow][quad * 8];
        for (int ni = 0; ni < 5; ni++) {
            bf16x8 wf = *(const bf16x8*)&Ws[ni * 16 + lrow][quad * 8];
            acc[ni] = __builtin_amdgcn_mfma_f32_16x16x32_bf16(af, wf, acc[ni], 0, 0, 0);
        }
    }
    float* pout = part + (size_t)ks * MROWS * NXP;
    for (int ni = 0; ni < 5; ni++) {
        int col = ni * 16 + lrow;
        for (int r = 0; r < 4; r++) {
            int row = m0 + wm + quad * 4 + r;
            pout[(size_t)row * NXP + col] = acc[ni][r];
        }
    }
}

// reduce split-K partials -> xdbl f32 + padded bf16 dt
__global__ __launch_bounds__(256) void xp_reduce_k(const float* __restrict__ part,
                                                   float* __restrict__ xdbl,
                                                   bf16* __restrict__ dtbf) {
    int idx = blockIdx.x * 256 + threadIdx.x;
    if (idx >= MROWS * NXP) return;
    float s = 0.f;
    for (int j = 0; j < KSPLIT; j++) s += part[(size_t)j * MROWS * NXP + idx];
    xdbl[idx] = s;
    int m = idx / NXP, c = idx - m * NXP;
    if (c < DTRANK)      dtbf[m * DTPAD + c] = (bf16)s;
    else if (c < DTPAD)  dtbf[m * DTPAD + c] = (bf16)0.f;
}

// ---------------------------------------------------------------- causal depthwise conv + silu + gate (4-wide, bf16 outputs)
__global__ __launch_bounds__(256) void conv_silu_k(const bf16* __restrict__ xz,
                                                   const float* __restrict__ cw,
                                                   const float* __restrict__ cb,
                                                   bf16* __restrict__ xcb,
                                                   bf16* __restrict__ gzb) {
    int t = blockIdx.x * 256 + threadIdx.x;
    if (t >= MROWS * (DI / 4)) return;
    int m = t / (DI / 4);
    int d = (t - m * (DI / 4)) * 4;
    int l = m & (LL - 1);
    float acc[4];
    floatx4 cwv[4];
    for (int q = 0; q < 4; q++) {
        acc[q] = cb[d + q];
        cwv[q] = *(const floatx4*)&cw[(d + q) * 4];
    }
    for (int k = 0; k < 4; k++) {
        int lp = l - 3 + k;
        if (lp >= 0) {
            bf16x4 v = *(const bf16x4*)&xz[(size_t)(m - 3 + k) * (2 * DI) + d];
            for (int q = 0; q < 4; q++) acc[q] += (float)v[q] * cwv[q][k];
        }
    }
    bf16x4 xo, go;
    bf16x4 z4 = *(const bf16x4*)&xz[(size_t)m * (2 * DI) + DI + d];
    for (int q = 0; q < 4; q++) {
        float s = acc[q] / (1.f + __expf(-acc[q]));
        xo[q] = (bf16)s;
        float zv = (float)z4[q];
        go[q] = (bf16)(zv / (1.f + __expf(-zv)));
    }
    *(bf16x4*)&xcb[(size_t)m * DI + d] = xo;
    *(bf16x4*)&gzb[(size_t)m * DI + d] = go;
}

// ---------------------------------------------------------------- selective scan v8 (scanB)
// Each lane owns (d, 4 consecutive n) with h[4] in registers; quad DPP y-reduce;
// one barrier; direct global emit. Grid 768 blocks = 3 waves/SIMD all resident.
__global__ __launch_bounds__(256) void scanB_k(const bf16* __restrict__ dtb,
                                               const bf16* __restrict__ wdt,
                                               const float* __restrict__ dtbias,
                                               const bf16* __restrict__ xcb,
                                               const float* __restrict__ xdbl,
                                               const float* __restrict__ A_log,
                                               float* __restrict__ Pbuf,
                                               float* __restrict__ Sbuf,
                                               float2* __restrict__ ylsc) {
    const int b   = blockIdx.y;
    const int d0  = blockIdx.x * DBLK;
    const int c   = blockIdx.z;
    const int tid = threadIdx.x;
    const int wv  = tid >> 6;
    const int lane = tid & 63;
    const int lr  = lane & 15;
    const int q   = lane >> 4;
    const int l0  = c * CLEN;
    const int dl  = tid >> 2;          // 0..63: d within block (scan phase)
    const int nq  = tid & 3;           // n-quad (aligned with DPP quads)

    __shared__ __align__(16) float sdp[DBLK][68];      // [d][l] dv  (17.4 KB)
    __shared__ __align__(16) bf16  sxc[CLEN][DBLK];    // [l][d] conv out, DMA (8 KB)
    __shared__ __align__(16) float sB[CLEN][20];       // [l][n] B (5.1 KB)
    __shared__ __align__(16) float sC[CLEN][20];       // [l][n] C (5.1 KB)

    // ---- stage: xc via DMA (drains under pack) ----
    {
        int t2 = tid;
        ld16((char*)&sxc[0][0] + (t2 & ~63) * 16,
             xcb + (size_t)(b * LL + l0 + (t2 >> 3)) * DI + d0 + (t2 & 7) * 8);
        t2 = tid + 256;
        ld16((char*)&sxc[0][0] + (t2 & ~63) * 16,
             xcb + (size_t)(b * LL + l0 + (t2 >> 3)) * DI + d0 + (t2 & 7) * 8);
    }

    // ---- B/C: global regs -> transposed LDS ----
    {
        float Bv[4], Cv[4];
        #pragma unroll
        for (int k2 = 0; k2 < 4; ++k2) {
            int ii = (tid + 256 * k2) >> 4;
            const float* p = &xdbl[(size_t)(b * LL + l0 + ii) * NXP + DTRANK + (tid & 15)];
            Bv[k2] = p[0];
            Cv[k2] = p[DSTATE];
        }
        #pragma unroll
        for (int k2 = 0; k2 < 4; ++k2) {
            int ii = (tid + 256 * k2) >> 4;
            sB[ii][tid & 15] = Bv[k2];
            sC[ii][tid & 15] = Cv[k2];
        }
    }

    // ---- per-thread a2[4] for (d, 4 n) ----
    float4 a2q;
    {
        float4 al = *(const float4*)&A_log[(size_t)(d0 + dl) * DSTATE + nq * 4];
        a2q.x = -__expf(al.x) * LOG2E;
        a2q.y = -__expf(al.y) * LOG2E;
        a2q.z = -__expf(al.z) * LOG2E;
        a2q.w = -__expf(al.w) * LOG2E;
    }

    // ---- pack: delta = softplus(dt @ w_dt^T + bias) via MFMA, regs only -> sdp ----
    {
        const bf16* ar = &dtb[(size_t)(b * LL + l0 + 16 * wv + lr) * DTPAD + q * 8];
        bf16x8 a0 = *(const bf16x8*)ar;
        bf16x8 a1 = *(const bf16x8*)(ar + 32);
        #pragma unroll
        for (int j = 0; j < 4; ++j) {
            const bf16* wr = &wdt[(size_t)(d0 + 16 * j + lr) * DTPAD + q * 8];
            bf16x8 w0 = *(const bf16x8*)wr;
            bf16x8 w1 = *(const bf16x8*)(wr + 32);
            floatx4 dacc = (floatx4){0.f, 0.f, 0.f, 0.f};
            dacc = __builtin_amdgcn_mfma_f32_16x16x32_bf16(a0, w0, dacc, 0, 0, 0);
            dacc = __builtin_amdgcn_mfma_f32_16x16x32_bf16(a1, w1, dacc, 0, 0, 0);
            float bi = dtbias[d0 + 16 * j + lr];
            #pragma unroll
            for (int r = 0; r < 4; ++r) {
                int l = 16 * wv + q * 4 + r;
                sdp[16 * j + lr][l] = softplus_fast(dacc[r] + bi);
            }
        }
    }

    wait_vm0();        // sxc DMA landed (hidden under pack)
    __syncthreads();   // the kernel's single barrier

    // ---- 64-step scan: h[4] in regs, quad DPP y-reduce, direct global emit ----
    {
        float4 hq = make_float4(0.f, 0.f, 0.f, 0.f);
        float sdc = 0.f;
        const float* dvrow = &sdp[dl][0];
        const unsigned short* xcp = (const unsigned short*)&sxc[0][0] + dl;
        for (int g = 0; g < 16; ++g) {
            float4 dvv = *(const float4*)&dvrow[4 * g];
            float2 yst[4];
            #pragma unroll
            for (int i2 = 0; i2 < 4; ++i2) {
                int i = 4 * g + i2;
                float dv = (i2 == 0) ? dvv.x : (i2 == 1) ? dvv.y : (i2 == 2) ? dvv.z : dvv.w;
                float xcv = __int_as_float((unsigned)xcp[i * DBLK] << 16);
                float du = dv * xcv;
                float4 Bq = *(const float4*)&sB[i][4 * nq];
                float4 Cq = *(const float4*)&sC[i][4 * nq];
                hq.x = __builtin_fmaf(exp2_raw(a2q.x * dv), hq.x, du * Bq.x);
                hq.y = __builtin_fmaf(exp2_raw(a2q.y * dv), hq.y, du * Bq.y);
                hq.z = __builtin_fmaf(exp2_raw(a2q.z * dv), hq.z, du * Bq.z);
                hq.w = __builtin_fmaf(exp2_raw(a2q.w * dv), hq.w, du * Bq.w);
                float y = __builtin_fmaf(Cq.w, hq.w,
                          __builtin_fmaf(Cq.z, hq.z,
                          __builtin_fmaf(Cq.y, hq.y, Cq.x * hq.x)));
                y = quad4_sum(y);
                sdc += dv;
                yst[i2] = make_float2(y, sdc);
            }
            if (nq == 0) {
                size_t base = (size_t)(b * LL + l0 + 4 * g) * DI + d0 + dl;
                ylsc[base]          = yst[0];
                ylsc[base + DI]     = yst[1];
                ylsc[base + 2 * DI] = yst[2];
                ylsc[base + 3 * DI] = yst[3];
            }
        }
        // chunk (P, S) per (d, n): float4 per thread, fully coalesced
        float4 Pq;
        Pq.x = exp2_raw(a2q.x * sdc);
        Pq.y = exp2_raw(a2q.y * sdc);
        Pq.z = exp2_raw(a2q.z * sdc);
        Pq.w = exp2_raw(a2q.w * sdc);
        size_t o = (((size_t)c * BB + b) * DI + (d0 + dl)) * DSTATE + nq * 4;
        *(float4*)&Pbuf[o] = Pq;
        *(float4*)&Sbuf[o] = make_float4(hq.x, hq.y, hq.z, hq.w);
    }
}

// Prefix-compose (P,S) over chunks -> H0T[c][n][d] = h entering chunk c (transposed).
__global__ __launch_bounds__(256) void compose_k(const float* __restrict__ P,
                                                 const float* __restrict__ S,
                                                 float* __restrict__ H0T) {
    int idx = blockIdx.x * 256 + threadIdx.x;   // over BB*DI*DSTATE, (b,d,n) order
    const size_t stride = (size_t)BB * DI * DSTATE;
    int b = idx / (DI * DSTATE);
    int rest = idx - b * (DI * DSTATE);
    int d = rest >> 4;
    int n = rest & 15;
    float h = 0.f;
    #pragma unroll
    for (int c = 0; c < NC; ++c) {
        H0T[((size_t)c * BB + b) * (DSTATE * DI) + (size_t)n * DI + d] = h;
        h = __builtin_fmaf(P[(size_t)c * stride + idx], h, S[(size_t)c * stride + idx]);
    }
}

// Parallel correction: y = (yloc + sum_n C*exp2(a2*Scum)*h0 + xc*D) * gz.
// grid (24, BB, NC); thread handles 4 l's (stride 16 in chunk) x 4 consecutive d.
__global__ __launch_bounds__(256) void corr_k(const float2* __restrict__ ylsc,
                                              const float* __restrict__ xdbl,
                                              const float* __restrict__ H0T,
                                              const float* __restrict__ a2T,
                                              const bf16* __restrict__ xcb,
                                              const bf16* __restrict__ gzb,
                                              const float* __restrict__ Dskip,
                                              bf16* __restrict__ ybf) {
    const int b = blockIdx.y, c = blockIdx.z;
    const int tid = threadIdx.x;
    const int t6 = blockIdx.x * 256 + tid;        // 0..6143
    const int dq   = (t6 % 384) * 4;              // d quad
    const int loff = t6 / 384;                    // 0..15

    __shared__ __align__(16) float sC[CLEN][16];  // C tile (d-independent)
    {
        int l = tid >> 2, nn = (tid & 3) * 4;
        *(float4*)&sC[l][nn] =
            *(const float4*)&xdbl[(size_t)(b * LL + c * CLEN + l) * NXP + DTRANK + DSTATE + nn];
    }
    __syncthreads();

    const float* h0base = H0T + ((size_t)c * BB + b) * (DSTATE * DI);
    int m0_ = b * LL + c * CLEN + loff;
    floatx4 acc[4];
    float4 sc[4];
    #pragma unroll
    for (int s = 0; s < 4; ++s) {
        size_t mo = (size_t)(m0_ + s * 16) * DI + dq;
        float4 u0 = *(const float4*)&ylsc[mo];       // (yl0,sc0,yl1,sc1)
        float4 u1 = *(const float4*)&ylsc[mo + 2];   // (yl2,sc2,yl3,sc3)
        acc[s] = (floatx4){u0.x, u0.z, u1.x, u1.z};
        sc[s]  = make_float4(u0.y, u0.w, u1.y, u1.w);
    }
    #pragma unroll
    for (int n = 0; n < DSTATE; ++n) {
        float4 a2v = *(const float4*)&a2T[(size_t)n * DI + dq];
        float4 h0v = *(const float4*)&h0base[(size_t)n * DI + dq];
        #pragma unroll
        for (int s = 0; s < 4; ++s) {
            float Cn = sC[loff + s * 16][n];
            acc[s][0] = __builtin_fmaf(Cn * h0v.x, exp2_raw(a2v.x * sc[s].x), acc[s][0]);
            acc[s][1] = __builtin_fmaf(Cn * h0v.y, exp2_raw(a2v.y * sc[s].y), acc[s][1]);
            acc[s][2] = __builtin_fmaf(Cn * h0v.z, exp2_raw(a2v.z * sc[s].z), acc[s][2]);
            acc[s][3] = __builtin_fmaf(Cn * h0v.w, exp2_raw(a2v.w * sc[s].w), acc[s][3]);
        }
    }
    float4 Dsk = *(const float4*)&Dskip[dq];
    #pragma unroll
    for (int s = 0; s < 4; ++s) {
        size_t mo = (size_t)(m0_ + s * 16) * DI + dq;
        bf16x4 xc4 = *(const bf16x4*)&xcb[mo];
        bf16x4 gz4 = *(const bf16x4*)&gzb[mo];
        bf16x4 yo;
        yo[0] = (bf16)((acc[s][0] + (float)xc4[0] * Dsk.x) * (float)gz4[0]);
        yo[1] = (bf16)((acc[s][1] + (float)xc4[1] * Dsk.y) * (float)gz4[1]);
        yo[2] = (bf16)((acc[s][2] + (float)xc4[2] * Dsk.z) * (float)gz4[2]);
        yo[3] = (bf16)((acc[s][3] + (float)xc4[3] * Dsk.w) * (float)gz4[3]);
        *(bf16x4*)&ybf[mo] = yo;
    }
}

// ---------------------------------------------------------------- head
__global__ __launch_bounds__(256) void head_norm_k(const float* __restrict__ x,
                                                   const float* __restrict__ fnw,
                                                   float* __restrict__ xn_buf) {
    int b = blockIdx.x;
    int tid = threadIdx.x;
    const float* xr = x + ((size_t)b * LL + (LL - 1)) * DD;
    __shared__ float sred[4];
    float v[3]; float ss = 0.f;
    for (int j = 0; j < 3; j++) { v[j] = xr[tid + j * 256]; ss += v[j] * v[j]; }
    for (int o = 1; o < 64; o <<= 1) ss += __shfl_xor(ss, o, 64);
    if ((tid & 63) == 0) sred[tid >> 6] = ss;
    __syncthreads();
    float scale = rsqrtf((sred[0] + sred[1] + sred[2] + sred[3]) / (float)DD + 1e-6f);
    for (int j = 0; j < 3; j++) {
        int c = tid + j * 256;
        xn_buf[(size_t)b * DD + c] = v[j] * scale * fnw[c];
    }
}

__global__ __launch_bounds__(256) void head_h1_k(const float* __restrict__ xn_buf,
                                                 const float* __restrict__ h1w,
                                                 const float* __restrict__ h1b,
                                                 float* __restrict__ h_buf) {
    int b  = blockIdx.x;
    int o0 = blockIdx.y * 64;
    int tid = threadIdx.x;
    __shared__ float sx[DD];
    for (int c = tid; c < DD; c += 256) sx[c] = xn_buf[(size_t)b * DD + c];
    __syncthreads();
    int wave = tid >> 6, lane = tid & 63;
    for (int j = 0; j < 16; j++) {
        int o = o0 + wave * 16 + j;
        const float* wrow = h1w + (size_t)o * DD;
        float acc = 0.f;
        for (int k = 0; k < 12; k++) {
            int c = lane + 64 * k;
            acc += wrow[c] * sx[c];
        }
        for (int off = 1; off < 64; off <<= 1) acc += __shfl_xor(acc, off, 64);
        if (lane == 0) h_buf[(size_t)b * DD + o] = acc + h1b[o];
    }
}

__global__ __launch_bounds__(256) void head_out_k(const float* __restrict__ h_buf,
                                                  const float* __restrict__ hnw,
                                                  const float* __restrict__ h2w,
                                                  const float* __restrict__ h2b,
                                                  float* __restrict__ out) {
    int b = blockIdx.x;
    int tid = threadIdx.x;
    __shared__ float hh[DD];
    __shared__ float sred[4];
    const float* hr = h_buf + (size_t)b * DD;
    float ss = 0.f;
    for (int c = tid; c < DD; c += 256) { float v = hr[c]; ss += v * v; }
    for (int o = 1; o < 64; o <<= 1) ss += __shfl_xor(ss, o, 64);
    if ((tid & 63) == 0) sred[tid >> 6] = ss;
    __syncthreads();
    float sc = rsqrtf((sred[0] + sred[1] + sred[2] + sred[3]) / (float)DD + 1e-6f);
    for (int c = tid; c < DD; c += 256) {
        float v = hr[c] * sc * hnw[c];
        hh[c] = 0.5f * v * (1.f + erff(v * 0.70710678118f));
    }
    __syncthreads();
    int w = tid >> 6, lane = tid & 63;
    for (int j = w; j < 10; j += 4) {
        float acc = 0.f;
        const float* wrow = h2w + (size_t)j * DD;
        for (int c = lane; c < DD; c += 64) acc += hh[c] * wrow[c];
        for (int o = 1; o < 64; o <<= 1) acc += __shfl_xor(acc, o, 64);
        if (lane == 0) out[b * 10 + j] = acc + h2b[j];
    }
}

// ----------------------------------------------------------------
extern "C" void kernel_launch(void* const* d_in, const int* in_sizes, int n_in,
                              void* d_out, int out_size, void* d_ws, size_t ws_size,
                              hipStream_t stream) {
    const float* x_in      = (const float*)d_in[0];
    const float* norm_w    = (const float*)d_in[1];
    const float* in_proj_w = (const float*)d_in[2];
    const float* conv_w    = (const float*)d_in[3];
    const float* conv_b    = (const float*)d_in[4];
    const float* x_proj_w  = (const float*)d_in[5];
    const float* dt_proj_w = (const float*)d_in[6];
    const float* dt_proj_b = (const float*)d_in[7];
    const float* A_log     = (const float*)d_in[8];
    const float* D_skip    = (const float*)d_in[9];
    const float* out_proj_w= (const float*)d_in[10];
    const float* fnw       = (const float*)d_in[11];
    const float* h1w       = (const float*)d_in[12];
    const float* h1b       = (const float*)d_in[13];
    const float* hnw       = (const float*)d_in[14];
    const float* h2w       = (const float*)d_in[15];
    const float* h2b       = (const float*)d_in[16];
    float* out = (float*)d_out;

    char* ws = (char*)d_ws;
    size_t off = 0;
    auto alloc = [&](size_t bytes) -> void* {
        void* p = ws + off;
        off += (bytes + 255) & ~(size_t)255;
        return p;
    };
    bf16* w_in  = (bf16*)alloc((size_t)N1 * 2);
    bf16* w_xp  = (bf16*)alloc((size_t)N2 * 2);
    bf16* w_dt  = (bf16*)alloc((size_t)N3 * 2);
    bf16* w_out = (bf16*)alloc((size_t)N4 * 2);
    float* a2T  = (float*)alloc((size_t)N5 * 4);
    bf16* xn_bf = (bf16*)alloc((size_t)MROWS * DD * 2);
    bf16* xz_bf = (bf16*)alloc((size_t)MROWS * 2 * DI * 2);
    bf16* xc_bf = (bf16*)alloc((size_t)MROWS * DI * 2);
    bf16* gz_bf = (bf16*)alloc((size_t)MROWS * DI * 2);
    float* xdbl = (float*)alloc((size_t)MROWS * NXP * 4);
    bf16* dt_bf = (bf16*)alloc((size_t)MROWS * DTPAD * 2);
    bf16* y_bf  = (bf16*)alloc((size_t)MROWS * DI * 2);
    float* x_buf= (float*)alloc((size_t)MROWS * DD * 4);
    float* Pbuf = (float*)alloc((size_t)NC * BB * DI * DSTATE * 4);
    float* Sbuf = (float*)alloc((size_t)NC * BB * DI * DSTATE * 4);
    float* H0T  = (float*)alloc((size_t)NC * BB * DI * DSTATE * 4);
    float2* ylsc= (float2*)alloc((size_t)MROWS * DI * 8);
    float* xnl  = (float*)alloc((size_t)BB * DD * 4);
    float* hbuf = (float*)alloc((size_t)BB * DD * 4);
    float* xp_part = (float*)alloc((size_t)KSPLIT * MROWS * NXP * 4);
    float* op_part = (float*)alloc((size_t)OPKS * MROWS * DD * 4);

    // all weight conversions + a2T table in one launch
    {
        int ntot = N1 + N2 + N3 + N4 + N5;
        cvt_all_k<<<(ntot + 255) / 256, 256, 0, stream>>>(
            in_proj_w, x_proj_w, dt_proj_w, out_proj_w, A_log,
            w_in, w_xp, w_dt, w_out, a2T);
    }

    for (int i = 0; i < 4; i++) {
        const float* x_src = (i == 0) ? x_in : x_buf;
        // 1. rmsnorm (layer 0 only; later layers get xn_bf from fused op_reduce_norm)
        if (i == 0)
            rmsnorm_k<<<MROWS, 256, 0, stream>>>(x_src, norm_w, xn_bf);
        // 2. in_proj: (2048 x 3072), bf16 out — 64-row tiles, 768 blocks (3/CU)
        gemm_bt<1, 64><<<dim3(MROWS / 64, 3072 / 128), 256, 0, stream>>>(
            xn_bf, w_in + (size_t)i * 3072 * 768, nullptr, xz_bf,
            MROWS, 2 * DI, DD);
        // 3. causal conv + silu + silu(z) gate (bf16 outputs)
        conv_silu_k<<<(MROWS * (DI / 4) + 255) / 256, 256, 0, stream>>>(
            xz_bf, conv_w + (size_t)i * DI * 4, conv_b + (size_t)i * DI, xc_bf, gz_bf);
        // 4. x_proj split-K + reduce -> xdbl f32 + padded bf16 dt
        gemm_xp<<<dim3(MROWS / 64, KSPLIT), 256, 0, stream>>>(
            xc_bf, w_xp + (size_t)i * NXP * DI, xp_part);
        xp_reduce_k<<<(MROWS * NXP + 255) / 256, 256, 0, stream>>>(xp_part, xdbl, dt_bf);
        // 5. scan v8: 4-state lanes, all-resident grid -> compose -> parallel corr
        scanB_k<<<dim3(DI / DBLK, BB, NC), 256, 0, stream>>>(
            dt_bf, w_dt + (size_t)i * DI * DTPAD, dt_proj_b + (size_t)i * DI,
            xc_bf, xdbl, A_log + (size_t)i * DI * DSTATE, Pbuf, Sbuf, ylsc);
        compose_k<<<(BB * DI * DSTATE) / 256, 256, 0, stream>>>(Pbuf, Sbuf, H0T);
        corr_k<<<dim3(24, BB, NC), 256, 0, stream>>>(
            ylsc, xdbl, H0T, a2T + (size_t)i * DSTATE * DI,
            xc_bf, gz_bf, D_skip + (size_t)i * DI, y_bf);
        // 6. out_proj split-K -> partials (64-row tiles, 768 blocks); fused reduce
        gemm_bt<5, 64><<<dim3(MROWS / 64, DD / 128, OPKS), 256, 0, stream>>>(
            y_bf, w_out + (size_t)i * DD * DI, op_part, nullptr,
            MROWS, DD, DI);
        op_reduce_norm_k<<<MROWS, 256, 0, stream>>>(
            op_part, x_src, norm_w + ((i + 1) & 3) * DD, x_buf, xn_bf);
    }

    head_norm_k<<<BB, 256, 0, stream>>>(x_buf, fnw, xnl);
    head_h1_k<<<dim3(BB, DD / 64), 256, 0, stream>>>(xnl, h1w, h1b, hbuf);
    head_out_k<<<BB, 256, 0, stream>>>(hbuf, hnw, h2w, h2b, out);
}